// Round 1
// baseline (603.904 us; speedup 1.0000x reference)
//
#include <hip/hip_runtime.h>
#include <cstdint>
#include <cstddef>

#define B_ 16
#define Q_ 4096
#define G_ 128
#define C_ 80

__device__ __forceinline__ bool lexless(float v1, int q1, float v2, int q2) {
    return v1 < v2 || (v1 == v2 && q1 < q2);
}

// ---------------------------------------------------------------------------
// Kernel 1: dense pairwise cost / iou.  One block per (b,q), one thread per g.
// Also zero-fills the matching plane.
// ---------------------------------------------------------------------------
__global__ __launch_bounds__(128) void cost_kernel(
    const float* __restrict__ logits,   // (B,Q,C)
    const float* __restrict__ pboxes,   // (B,Q,8)
    const float* __restrict__ gboxes,   // (B,G,8)
    const int*   __restrict__ glabels,  // (B,G)
    float* __restrict__ out_match,
    float* __restrict__ out_cost,
    float* __restrict__ out_iou)
{
    const int q = blockIdx.x, b = blockIdx.y, g = threadIdx.x;
    __shared__ float pc[8];
    __shared__ int s_fg;
    if (g < 8) pc[g] = pboxes[((size_t)b * Q_ + q) * 8 + g];
    if (g == 0) s_fg = 0;
    __syncthreads();

    const float p0 = pc[0], p1 = pc[1], p2 = pc[2], p3 = pc[3];
    const float p4 = pc[4], p5v = pc[5], p6 = pc[6], p7 = pc[7];
    const float pxc = (p0 + p2 + p4 + p6) * 0.25f;
    const float pyc = (p1 + p3 + p5v + p7) * 0.25f;
    const float pw = sqrtf((p0 - p2) * (p0 - p2) + (p1 - p3) * (p1 - p3));
    const float ph = sqrtf((p2 - p4) * (p2 - p4) + (p3 - p5v) * (p3 - p5v));
    const float pax0 = pxc - pw * 0.5f, pay0 = pyc - ph * 0.5f;
    const float pax1 = pxc + pw * 0.5f, pay1 = pyc + ph * 0.5f;
    const float parea = (pax1 - pax0) * (pay1 - pay0);

    const float4* gb4 = (const float4*)(gboxes + ((size_t)b * G_ + g) * 8);
    const float4 ga = gb4[0], gbv = gb4[1];
    const float g0 = ga.x, g1 = ga.y, g2 = ga.z, g3 = ga.w;
    const float g4 = gbv.x, g5 = gbv.y, g6 = gbv.z, g7 = gbv.w;
    const float gxc = (g0 + g2 + g4 + g6) * 0.25f;
    const float gyc = (g1 + g3 + g5 + g7) * 0.25f;
    const float gw = sqrtf((g0 - g2) * (g0 - g2) + (g1 - g3) * (g1 - g3));
    const float gh = sqrtf((g2 - g4) * (g2 - g4) + (g3 - g5) * (g3 - g5));
    const float gax0 = gxc - gw * 0.5f, gay0 = gyc - gh * 0.5f;
    const float gax1 = gxc + gw * 0.5f, gay1 = gyc + gh * 0.5f;
    const float garea = (gax1 - gax0) * (gay1 - gay0);

    // in-box test (fg mask): cdist <= gt_tri_area / (aabb_diag/32)
    const float v1x = g2 - g0, v1y = g3 - g1;
    const float v2x = g4 - g0, v2y = g5 - g1;
    const float gt_area = fabsf(v1x * v2y - v1y * v2x) * 0.5f;
    const float mxx = fmaxf(fmaxf(g0, g2), fmaxf(g4, g6));
    const float mnx = fminf(fminf(g0, g2), fminf(g4, g6));
    const float mxy = fmaxf(fmaxf(g1, g3), fmaxf(g5, g7));
    const float mny = fminf(fminf(g1, g3), fminf(g5, g7));
    const float dgx = mxx - mnx, dgy = mxy - mny;
    const float diag = sqrtf(dgx * dgx + dgy * dgy);
    const float radius = diag / 32.0f;
    const float dx = pxc - gxc, dy = pyc - gyc;
    const float cdist = sqrtf(dx * dx + dy * dy);
    if (cdist <= gt_area / radius) s_fg = 1;  // benign race, same value

    // axis-aligned IoU on (cx,cy,w,h) boxes
    const float ltx = fmaxf(pax0, gax0), lty = fmaxf(pay0, gay0);
    const float rbx = fminf(pax1, gax1), rby = fminf(pay1, gay1);
    const float iw = fmaxf(rbx - ltx, 0.f), ih = fmaxf(rby - lty, 0.f);
    const float inter = iw * ih;
    const float iou = inter / (parea + garea - inter + 1e-8f);

    // DIoU
    const float ew = fmaxf(pax1, gax1) - fminf(pax0, gax0);
    const float eh = fmaxf(pay1, gay1) - fminf(pay0, gay0);
    const float c2 = ew * ew + eh * eh + 1e-8f;
    const float d2 = dx * dx + dy * dy;
    const float diou = iou - d2 / c2;

    // L1 over the 8 corner coords
    const float l1 = fabsf(p0 - g0) + fabsf(p1 - g1) + fabsf(p2 - g2) + fabsf(p3 - g3)
                   + fabsf(p4 - g4) + fabsf(p5v - g5) + fabsf(p6 - g6) + fabsf(p7 - g7);

    // focal class cost at this gt's label
    const int lab = glabels[b * G_ + g];
    const float x = logits[((size_t)b * Q_ + q) * C_ + lab];
    float p;
    if (x >= 0.f) { const float e = expf(-x); p = 1.f / (1.f + e); }
    else          { const float e = expf(x);  p = e / (1.f + e); }
    const float pos = 0.25f * (1.f - p) * (1.f - p) * (-logf(p + 1e-8f));
    const float neg = 0.75f * p * p * (-logf(1.f - p + 1e-8f));
    const float cclass = pos - neg;

    __syncthreads();
    const bool fg = (s_fg != 0);
    // NOTE reference: cost = 5*l1 + 2*cls + 2*(+diou) + 10000*(!fg)
    const float cost = 5.f * l1 + 2.f * cclass + 2.f * diou + (fg ? 0.f : 10000.f);

    const size_t o = ((size_t)b * Q_ + q) * (size_t)G_ + g;
    out_cost[o] = cost;
    out_iou[o]  = iou;
    out_match[o] = 0.f;
}

// ---------------------------------------------------------------------------
// Kernel 2: per (b,g) column — dyn_k = clip(int(sum top5 iou),1,5) (<=5 since
// iou<=1), then scatter 1.0 at the dyn_k lex-smallest (cost,q) rows.
// ---------------------------------------------------------------------------
__global__ __launch_bounds__(256) void select_kernel(
    const float* __restrict__ out_cost,
    const float* __restrict__ out_iou,
    float* __restrict__ out_match)
{
    const int g = blockIdx.x, b = blockIdx.y, tid = threadIdx.x;
    const size_t colbase = (size_t)b * Q_ * G_ + g;

    __shared__ float s_v[256 * 5];
    __shared__ int   s_q[256 * 5];

    // ---- phase A: top-5 iou values (descending) ----
    float tv[5] = {-1e38f, -1e38f, -1e38f, -1e38f, -1e38f};
    for (int q = tid; q < Q_; q += 256) {
        const float v = out_iou[colbase + (size_t)q * G_];
        if (v > tv[4]) {
            int k = 4;
            while (k > 0 && v > tv[k - 1]) { tv[k] = tv[k - 1]; --k; }
            tv[k] = v;
        }
    }
    for (int i = 0; i < 5; ++i) s_v[tid * 5 + i] = tv[i];
    __syncthreads();
    for (int s = 128; s > 0; s >>= 1) {
        if (tid < s) {
            float a[5], bb[5], r[5];
            for (int i = 0; i < 5; ++i) { a[i] = s_v[tid * 5 + i]; bb[i] = s_v[(tid + s) * 5 + i]; }
            int ia = 0, ib = 0;
            for (int k = 0; k < 5; ++k) {
                if (a[ia] >= bb[ib]) r[k] = a[ia++]; else r[k] = bb[ib++];
            }
            for (int i = 0; i < 5; ++i) s_v[tid * 5 + i] = r[i];
        }
        __syncthreads();
    }
    int dynk = 1;
    if (tid == 0) {
        const float s = s_v[0] + s_v[1] + s_v[2] + s_v[3] + s_v[4];
        dynk = (int)s;               // trunc toward zero, s in [0,5]
        if (dynk < 1) dynk = 1;
        if (dynk > 5) dynk = 5;
    }
    __syncthreads();

    // ---- phase B: 5 lex-smallest (cost, q) ----
    float bv[5] = {1e38f, 1e38f, 1e38f, 1e38f, 1e38f};
    int   bq[5] = {0x7fffffff, 0x7fffffff, 0x7fffffff, 0x7fffffff, 0x7fffffff};
    for (int q = tid; q < Q_; q += 256) {
        const float v = out_cost[colbase + (size_t)q * G_];
        if (lexless(v, q, bv[4], bq[4])) {
            int k = 4;
            while (k > 0 && lexless(v, q, bv[k - 1], bq[k - 1])) {
                bv[k] = bv[k - 1]; bq[k] = bq[k - 1]; --k;
            }
            bv[k] = v; bq[k] = q;
        }
    }
    for (int i = 0; i < 5; ++i) { s_v[tid * 5 + i] = bv[i]; s_q[tid * 5 + i] = bq[i]; }
    __syncthreads();
    for (int s = 128; s > 0; s >>= 1) {
        if (tid < s) {
            float av[5], bv2[5], rv[5];
            int   aq[5], bq2[5], rq[5];
            for (int i = 0; i < 5; ++i) {
                av[i] = s_v[tid * 5 + i];       aq[i] = s_q[tid * 5 + i];
                bv2[i] = s_v[(tid + s) * 5 + i]; bq2[i] = s_q[(tid + s) * 5 + i];
            }
            int ia = 0, ib = 0;
            for (int k = 0; k < 5; ++k) {
                if (lexless(av[ia], aq[ia], bv2[ib], bq2[ib])) { rv[k] = av[ia]; rq[k] = aq[ia]; ++ia; }
                else                                           { rv[k] = bv2[ib]; rq[k] = bq2[ib]; ++ib; }
            }
            for (int i = 0; i < 5; ++i) { s_v[tid * 5 + i] = rv[i]; s_q[tid * 5 + i] = rq[i]; }
        }
        __syncthreads();
    }
    if (tid == 0) {
        for (int i = 0; i < dynk; ++i) {
            const int q = s_q[i];
            out_match[(size_t)b * Q_ * G_ + (size_t)q * G_ + g] = 1.0f;
        }
    }
}

// ---------------------------------------------------------------------------
// Kernel 3: per-batch sequential refinement loop.  One block per batch.
// Invariant: after each _dedup every row has <= 1 match -> row_match[q].
// The +100000 penalty is row-constant, so the dedup row-argmin is
// precomputable; per-column argmins are decided among zero-penalty rows, so
// cost+add is exact vs. the reference's accumulated c.
// ---------------------------------------------------------------------------
__global__ __launch_bounds__(256) void loop_kernel(
    const float* __restrict__ cost_all,
    float* __restrict__ match_all)
{
    const int b = blockIdx.x, tid = threadIdx.x;
    const float* costb = cost_all + (size_t)b * Q_ * G_;
    float* matchb = match_all + (size_t)b * Q_ * G_;

    __shared__ short rmatch[Q_];           // 8 KB: matched g per row, -1 = none
    __shared__ float addv[Q_];             // 16 KB: accumulated +100000 per row
    __shared__ unsigned char ramin[Q_];    // 4 KB: argmin_g cost[q,:] (first min)
    __shared__ unsigned char newg[Q_];     // 4 KB
    __shared__ int newh[Q_];               // 16 KB
    __shared__ int col_cnt[G_];
    __shared__ int unm_list[G_];
    __shared__ int amin_q[G_];
    __shared__ int n_unm;

    // init: row argmin, addv, row_match from initial matching (+ first dedup)
    for (int q = tid; q < Q_; q += 256) {
        const float4* cr = (const float4*)(costb + (size_t)q * G_);
        float mv = 1e38f; int mg = 0;
        for (int i = 0; i < G_ / 4; ++i) {
            const float4 c4 = cr[i];
            if (c4.x < mv) { mv = c4.x; mg = i * 4; }
            if (c4.y < mv) { mv = c4.y; mg = i * 4 + 1; }
            if (c4.z < mv) { mv = c4.z; mg = i * 4 + 2; }
            if (c4.w < mv) { mv = c4.w; mg = i * 4 + 3; }
        }
        ramin[q] = (unsigned char)mg;
        addv[q] = 0.f;
        const float4* mr = (const float4*)(matchb + (size_t)q * G_);
        int cnt = 0, gf = -1;
        for (int i = 0; i < G_ / 4; ++i) {
            const float4 m4 = mr[i];
            if (m4.x != 0.f) { if (!cnt) gf = i * 4;     ++cnt; }
            if (m4.y != 0.f) { if (!cnt) gf = i * 4 + 1; ++cnt; }
            if (m4.z != 0.f) { if (!cnt) gf = i * 4 + 2; ++cnt; }
            if (m4.w != 0.f) { if (!cnt) gf = i * 4 + 3; ++cnt; }
        }
        rmatch[q] = (cnt == 0) ? (short)-1 : (cnt == 1 ? (short)gf : (short)ramin[q]);
    }
    __syncthreads();
    if (tid < G_) col_cnt[tid] = 0;
    __syncthreads();
    for (int q = tid; q < Q_; q += 256)
        if (rmatch[q] >= 0) atomicAdd(&col_cnt[rmatch[q]], 1);
    __syncthreads();

    for (int it = 0; it < G_; ++it) {
        if (tid == 0) n_unm = 0;
        __syncthreads();
        if (tid < G_ && col_cnt[tid] == 0) {
            const int pidx = atomicAdd(&n_unm, 1);
            unm_list[pidx] = tid;
        }
        __syncthreads();
        const int nu = n_unm;
        if (nu == 0) break;

        // c += 100000 for matched rows (at iteration start); clear hit counters
        for (int q = tid; q < Q_; q += 256) {
            if (rmatch[q] >= 0) addv[q] += 100000.f;
            newh[q] = 0;
        }
        __syncthreads();

        // per-unmatched-column argmin_q (cost + add), one wave per column
        const int wv = tid >> 6, ln = tid & 63;
        for (int u = wv; u < nu; u += 4) {
            const int g = unm_list[u];
            float bv = 1e38f; int bq = 0x7fffffff;
            for (int q = ln; q < Q_; q += 64) {
                const float v = costb[(size_t)q * G_ + g] + addv[q];
                if (v < bv || (v == bv && q < bq)) { bv = v; bq = q; }
            }
            for (int off = 32; off > 0; off >>= 1) {
                const float ov = __shfl_xor(bv, off);
                const int   oq = __shfl_xor(bq, off);
                if (ov < bv || (ov == bv && oq < bq)) { bv = ov; bq = oq; }
            }
            if (ln == 0) amin_q[u] = bq;
        }
        __syncthreads();

        // apply hits
        if (tid < nu) {
            const int q = amin_q[tid];
            atomicAdd(&newh[q], 1);
            newg[q] = (unsigned char)unm_list[tid];  // only read when nh==1
        }
        __syncthreads();

        // per-row resolve (= hit + dedup)
        for (int q = tid; q < Q_; q += 256) {
            const int nh = newh[q];
            if (nh > 0) {
                const int total = nh + (rmatch[q] >= 0 ? 1 : 0);
                rmatch[q] = (total == 1) ? (short)newg[q] : (short)ramin[q];
            }
        }
        __syncthreads();
        if (tid < G_) col_cnt[tid] = 0;
        __syncthreads();
        for (int q = tid; q < Q_; q += 256)
            if (rmatch[q] >= 0) atomicAdd(&col_cnt[rmatch[q]], 1);
        __syncthreads();
    }

    // write final matching
    for (int idx = tid; idx < Q_ * G_ / 4; idx += 256) {
        const int q = idx >> 5;
        const int g0 = (idx & 31) << 2;
        const short rm = rmatch[q];
        float4 o;
        o.x = (rm == g0)     ? 1.f : 0.f;
        o.y = (rm == g0 + 1) ? 1.f : 0.f;
        o.z = (rm == g0 + 2) ? 1.f : 0.f;
        o.w = (rm == g0 + 3) ? 1.f : 0.f;
        ((float4*)(matchb))[idx] = o;
    }
}

extern "C" void kernel_launch(void* const* d_in, const int* in_sizes, int n_in,
                              void* d_out, int out_size, void* d_ws, size_t ws_size,
                              hipStream_t stream) {
    const float* logits  = (const float*)d_in[0];
    const float* pboxes  = (const float*)d_in[1];
    const float* gboxes  = (const float*)d_in[2];
    const int*   glabels = (const int*)d_in[3];

    float* out = (float*)d_out;
    const size_t BQG = (size_t)B_ * Q_ * G_;
    float* out_match = out;
    float* out_cost  = out + BQG;
    float* out_iou   = out + 2 * BQG;

    cost_kernel<<<dim3(Q_, B_), 128, 0, stream>>>(logits, pboxes, gboxes, glabels,
                                                  out_match, out_cost, out_iou);
    select_kernel<<<dim3(G_, B_), 256, 0, stream>>>(out_cost, out_iou, out_match);
    loop_kernel<<<B_, 256, 0, stream>>>(out_cost, out_match);
}

// Round 2
// 381.973 us; speedup vs baseline: 1.5810x; 1.5810x over previous
//
#include <hip/hip_runtime.h>
#include <cstdint>
#include <cstddef>

#define B_ 16
#define Q_ 4096
#define G_ 128
#define C_ 80
#define QCHUNK 128
#define NCH (Q_ / QCHUNK)   // 32 chunks

__device__ __forceinline__ bool lexless(float v1, int q1, float v2, int q2) {
    return v1 < v2 || (v1 == v2 && q1 < q2);
}

// ---------------------------------------------------------------------------
// Kernel A: fused cost/iou + per-chunk partial top5(iou) / bottom5(cost,q).
// Block = (chunk of 128 q's, batch). Thread: g = tid&127, qh = tid>>7.
// Writes: out_cost, out_iou (B,Q,G), costT (B,G,Q), partials (B,G,NCH,2,5).
// ---------------------------------------------------------------------------
__global__ __launch_bounds__(256) void fused_cost_kernel(
    const float* __restrict__ logits,
    const float* __restrict__ pboxes,
    const float* __restrict__ gboxes,
    const int*   __restrict__ glabels,
    float* __restrict__ out_cost,
    float* __restrict__ out_iou,
    float* __restrict__ costT,
    float* __restrict__ piou,
    float* __restrict__ pcv,
    int*   __restrict__ pcq)
{
    const int tid = threadIdx.x;
    const int g   = tid & 127;
    const int qh  = tid >> 7;
    const int ci  = blockIdx.x, b = blockIdx.y;
    const int q0  = ci * QCHUNK;

    __shared__ float pq[QCHUNK][16];   // 8 corners + 7 derived per q
    __shared__ int   fgf[QCHUNK];
    __shared__ float lbuf[16 * 80];    // logits for 16 staged q's

    // ---- per-thread gt constants ----
    const float4* gb4 = (const float4*)(gboxes + ((size_t)b * G_ + g) * 8);
    const float4 gA = gb4[0], gB = gb4[1];
    const float g0 = gA.x, g1 = gA.y, g2 = gA.z, g3 = gA.w;
    const float g4 = gB.x, g5 = gB.y, g6 = gB.z, g7 = gB.w;
    const float gxc = (g0 + g2 + g4 + g6) * 0.25f;
    const float gyc = (g1 + g3 + g5 + g7) * 0.25f;
    const float gw = sqrtf((g0 - g2) * (g0 - g2) + (g1 - g3) * (g1 - g3));
    const float gh = sqrtf((g2 - g4) * (g2 - g4) + (g3 - g5) * (g3 - g5));
    const float gax0 = gxc - gw * 0.5f, gay0 = gyc - gh * 0.5f;
    const float gax1 = gxc + gw * 0.5f, gay1 = gyc + gh * 0.5f;
    const float garea = (gax1 - gax0) * (gay1 - gay0);
    const float v1x = g2 - g0, v1y = g3 - g1, v2x = g4 - g0, v2y = g5 - g1;
    const float gt_area = fabsf(v1x * v2y - v1y * v2x) * 0.5f;
    const float mxx = fmaxf(fmaxf(g0, g2), fmaxf(g4, g6));
    const float mnx = fminf(fminf(g0, g2), fminf(g4, g6));
    const float mxy = fmaxf(fmaxf(g1, g3), fmaxf(g5, g7));
    const float mny = fminf(fminf(g1, g3), fminf(g5, g7));
    const float dgx = mxx - mnx, dgy = mxy - mny;
    const float radius = sqrtf(dgx * dgx + dgy * dgy) / 32.0f;
    const float thresh = gt_area / radius;
    const int lab = glabels[b * G_ + g];

    // ---- stage pred boxes for this chunk (coalesced float4) ----
    {
        const float4 v = ((const float4*)(pboxes + ((size_t)b * Q_ + q0) * 8))[tid];
        *(float4*)&pq[tid >> 1][(tid & 1) * 4] = v;
    }
    __syncthreads();
    // derived per-q values (threads 0..127, one q each) + fg init
    if (tid < QCHUNK) {
        const float* pr = pq[tid];
        const float p0 = pr[0], p1 = pr[1], p2 = pr[2], p3 = pr[3];
        const float p4 = pr[4], p5v = pr[5], p6 = pr[6], p7 = pr[7];
        const float pxc = (p0 + p2 + p4 + p6) * 0.25f;
        const float pyc = (p1 + p3 + p5v + p7) * 0.25f;
        const float pw = sqrtf((p0 - p2) * (p0 - p2) + (p1 - p3) * (p1 - p3));
        const float ph = sqrtf((p2 - p4) * (p2 - p4) + (p3 - p5v) * (p3 - p5v));
        pq[tid][8]  = pxc;
        pq[tid][9]  = pyc;
        pq[tid][10] = pxc - pw * 0.5f;
        pq[tid][11] = pyc - ph * 0.5f;
        pq[tid][12] = pxc + pw * 0.5f;
        pq[tid][13] = pyc + ph * 0.5f;
        pq[tid][14] = pw * ph;
        fgf[tid] = 0;
    }
    __syncthreads();

    // ---- pass 1: fg mask (any over g) ----
    const int lane0 = ((tid & 63) == 0);
    for (int i = 0; i < QCHUNK / 2; ++i) {
        const int ql = 2 * i + qh;
        const float dx = pq[ql][8] - gxc, dy = pq[ql][9] - gyc;
        const int in = sqrtf(dx * dx + dy * dy) <= thresh;
        const int anyin = __any(in);
        if (anyin && lane0) fgf[ql] = 1;
    }

    // ---- pass 2: full cost + running top5/bot5 ----
    float t0 = -1e38f, t1 = -1e38f, t2 = -1e38f, t3 = -1e38f, t4 = -1e38f;
    float c0v = 1e38f, c1v = 1e38f, c2v = 1e38f, c3v = 1e38f, c4v = 1e38f;
    int   c0q = 0x7fffffff, c1q = 0x7fffffff, c2q = 0x7fffffff,
          c3q = 0x7fffffff, c4q = 0x7fffffff;

    for (int sc = 0; sc < QCHUNK / 16; ++sc) {
        __syncthreads();  // also covers fgf hazard on sc==0
        for (int j = tid; j < 16 * 80; j += 256)
            lbuf[j] = logits[((size_t)b * Q_ + q0 + sc * 16) * 80 + j];
        __syncthreads();
        for (int jj = 0; jj < 8; ++jj) {
            const int ql = sc * 16 + 2 * jj + qh;
            const int q  = q0 + ql;
            const float* pr = pq[ql];
            const float p0 = pr[0], p1 = pr[1], p2 = pr[2], p3 = pr[3];
            const float p4 = pr[4], p5v = pr[5], p6 = pr[6], p7 = pr[7];
            const float pxc = pr[8], pyc = pr[9];
            const float pax0 = pr[10], pay0 = pr[11], pax1 = pr[12], pay1 = pr[13];
            const float parea = pr[14];

            const float l1 = fabsf(p0 - g0) + fabsf(p1 - g1) + fabsf(p2 - g2)
                           + fabsf(p3 - g3) + fabsf(p4 - g4) + fabsf(p5v - g5)
                           + fabsf(p6 - g6) + fabsf(p7 - g7);

            const float ltx = fmaxf(pax0, gax0), lty = fmaxf(pay0, gay0);
            const float rbx = fminf(pax1, gax1), rby = fminf(pay1, gay1);
            const float iw = fmaxf(rbx - ltx, 0.f), ih = fmaxf(rby - lty, 0.f);
            const float inter = iw * ih;
            const float iou = inter / (parea + garea - inter + 1e-8f);

            const float ew = fmaxf(pax1, gax1) - fminf(pax0, gax0);
            const float eh = fmaxf(pay1, gay1) - fminf(pay0, gay0);
            const float cc2 = ew * ew + eh * eh + 1e-8f;
            const float dx = pxc - gxc, dy = pyc - gyc;
            const float diou = iou - (dx * dx + dy * dy) / cc2;

            const float x = lbuf[(2 * jj + qh) * 80 + lab];
            float p;
            if (x >= 0.f) { const float e = expf(-x); p = 1.f / (1.f + e); }
            else          { const float e = expf(x);  p = e / (1.f + e); }
            const float pos = 0.25f * (1.f - p) * (1.f - p) * (-logf(p + 1e-8f));
            const float neg = 0.75f * p * p * (-logf(1.f - p + 1e-8f));
            const float cclass = pos - neg;

            const float cost = 5.f * l1 + 2.f * cclass + 2.f * diou
                             + (fgf[ql] ? 0.f : 10000.f);

            const size_t o = ((size_t)b * Q_ + q) * G_ + g;
            out_cost[o] = cost;
            out_iou[o]  = iou;
            costT[((size_t)b * G_ + g) * Q_ + q] = cost;

            // top-5 iou, descending (register scalars, unrolled insert)
            if (iou > t4) {
                if (iou > t0)      { t4 = t3; t3 = t2; t2 = t1; t1 = t0; t0 = iou; }
                else if (iou > t1) { t4 = t3; t3 = t2; t2 = t1; t1 = iou; }
                else if (iou > t2) { t4 = t3; t3 = t2; t2 = iou; }
                else if (iou > t3) { t4 = t3; t3 = iou; }
                else               { t4 = iou; }
            }
            // bottom-5 (cost, q) lexicographic
            if (lexless(cost, q, c4v, c4q)) {
                if (lexless(cost, q, c0v, c0q)) {
                    c4v = c3v; c4q = c3q; c3v = c2v; c3q = c2q; c2v = c1v; c2q = c1q;
                    c1v = c0v; c1q = c0q; c0v = cost; c0q = q;
                } else if (lexless(cost, q, c1v, c1q)) {
                    c4v = c3v; c4q = c3q; c3v = c2v; c3q = c2q; c2v = c1v; c2q = c1q;
                    c1v = cost; c1q = q;
                } else if (lexless(cost, q, c2v, c2q)) {
                    c4v = c3v; c4q = c3q; c3v = c2v; c3q = c2q; c2v = cost; c2q = q;
                } else if (lexless(cost, q, c3v, c3q)) {
                    c4v = c3v; c4q = c3q; c3v = cost; c3q = q;
                } else { c4v = cost; c4q = q; }
            }
        }
    }

    // ---- write partials: [B][G][NCH][2][5] ----
    const size_t pbase = (((size_t)b * G_ + g) * NCH + ci) * 10 + qh * 5;
    piou[pbase + 0] = t0; piou[pbase + 1] = t1; piou[pbase + 2] = t2;
    piou[pbase + 3] = t3; piou[pbase + 4] = t4;
    pcv[pbase + 0] = c0v; pcv[pbase + 1] = c1v; pcv[pbase + 2] = c2v;
    pcv[pbase + 3] = c3v; pcv[pbase + 4] = c4v;
    pcq[pbase + 0] = c0q; pcq[pbase + 1] = c1q; pcq[pbase + 2] = c2q;
    pcq[pbase + 3] = c3q; pcq[pbase + 4] = c4q;
}

// ---------------------------------------------------------------------------
// Kernel E: row argmin of cost (first-index tie-break).  One wave per row.
// ---------------------------------------------------------------------------
__global__ __launch_bounds__(256) void ramin_kernel(
    const float* __restrict__ cost, int* __restrict__ ramin)
{
    const int wv = threadIdx.x >> 6, ln = threadIdx.x & 63;
    const int row = blockIdx.x * 4 + wv;  // row in [0, B*Q)
    const float2 c2v = ((const float2*)(cost + (size_t)row * G_))[ln];
    float v; int gg;
    if (c2v.x <= c2v.y) { v = c2v.x; gg = 2 * ln; }
    else                { v = c2v.y; gg = 2 * ln + 1; }
    for (int off = 32; off > 0; off >>= 1) {
        const float ov = __shfl_xor(v, off);
        const int   og = __shfl_xor(gg, off);
        if (ov < v || (ov == v && og < gg)) { v = ov; gg = og; }
    }
    if (ln == 0) ramin[row] = gg;
}

// ---------------------------------------------------------------------------
// Kernel B: per (b,g) merge partials -> dyn_k, scatter (cnt, gsel) per row.
// ---------------------------------------------------------------------------
__global__ __launch_bounds__(128) void dynk_scatter_kernel(
    const float* __restrict__ piou,
    const float* __restrict__ pcv,
    const int*   __restrict__ pcq,
    int* __restrict__ cnt,
    int* __restrict__ gsel)
{
    const int g = threadIdx.x, b = blockIdx.x;
    const size_t base = ((size_t)b * G_ + g) * (NCH * 10);

    float t0 = -1e38f, t1 = -1e38f, t2 = -1e38f, t3 = -1e38f, t4 = -1e38f;
    #pragma unroll 4
    for (int j = 0; j < NCH * 10; ++j) {
        const float v = piou[base + j];
        if (v > t4) {
            if (v > t0)      { t4 = t3; t3 = t2; t2 = t1; t1 = t0; t0 = v; }
            else if (v > t1) { t4 = t3; t3 = t2; t2 = t1; t1 = v; }
            else if (v > t2) { t4 = t3; t3 = t2; t2 = v; }
            else if (v > t3) { t4 = t3; t3 = v; }
            else             { t4 = v; }
        }
    }
    const float s = t0 + t1 + t2 + t3 + t4;
    int dynk = (int)s;
    if (dynk < 1) dynk = 1;
    if (dynk > 5) dynk = 5;

    float c0v = 1e38f, c1v = 1e38f, c2v = 1e38f, c3v = 1e38f, c4v = 1e38f;
    int   c0q = 0x7fffffff, c1q = 0x7fffffff, c2q = 0x7fffffff,
          c3q = 0x7fffffff, c4q = 0x7fffffff;
    #pragma unroll 4
    for (int j = 0; j < NCH * 10; ++j) {
        const float v = pcv[base + j];
        const int   q = pcq[base + j];
        if (lexless(v, q, c4v, c4q)) {
            if (lexless(v, q, c0v, c0q)) {
                c4v = c3v; c4q = c3q; c3v = c2v; c3q = c2q; c2v = c1v; c2q = c1q;
                c1v = c0v; c1q = c0q; c0v = v; c0q = q;
            } else if (lexless(v, q, c1v, c1q)) {
                c4v = c3v; c4q = c3q; c3v = c2v; c3q = c2q; c2v = c1v; c2q = c1q;
                c1v = v; c1q = q;
            } else if (lexless(v, q, c2v, c2q)) {
                c4v = c3v; c4q = c3q; c3v = c2v; c3q = c2q; c2v = v; c2q = q;
            } else if (lexless(v, q, c3v, c3q)) {
                c4v = c3v; c4q = c3q; c3v = v; c3q = q;
            } else { c4v = v; c4q = q; }
        }
    }
    const int qs[5] = {c0q, c1q, c2q, c3q, c4q};
    for (int i = 0; i < dynk; ++i) {
        const int q = qs[i];
        atomicAdd(&cnt[b * Q_ + q], 1);
        gsel[b * Q_ + q] = g;   // only read when cnt==1 (single writer)
    }
}

// ---------------------------------------------------------------------------
// Kernel C: per-batch sequential refinement loop (LDS state, costT columns).
// ---------------------------------------------------------------------------
__global__ __launch_bounds__(256) void loop_kernel(
    const float* __restrict__ costT,
    const int* __restrict__ cnt,
    const int* __restrict__ gsel,
    const int* __restrict__ ramin,
    int* __restrict__ rmatch_final)
{
    const int b = blockIdx.x, tid = threadIdx.x;
    const float* ctb = costT + (size_t)b * G_ * Q_;

    __shared__ short rmatch[Q_];
    __shared__ __align__(16) float addv[Q_];
    __shared__ unsigned char s_ra[Q_];
    __shared__ unsigned char newg[Q_];
    __shared__ int newh[Q_];
    __shared__ int col_cnt[G_];
    __shared__ int unm_list[G_];
    __shared__ int amin_q[G_];
    __shared__ int n_unm;

    for (int q = tid; q < Q_; q += 256) {
        const int c  = cnt[b * Q_ + q];
        const int ra = ramin[b * Q_ + q];
        s_ra[q] = (unsigned char)ra;
        addv[q] = 0.f;
        rmatch[q] = (c == 0) ? (short)-1
                             : (c == 1 ? (short)gsel[b * Q_ + q] : (short)ra);
    }
    __syncthreads();
    if (tid < G_) col_cnt[tid] = 0;
    __syncthreads();
    for (int q = tid; q < Q_; q += 256)
        if (rmatch[q] >= 0) atomicAdd(&col_cnt[rmatch[q]], 1);
    __syncthreads();

    for (int it = 0; it < G_; ++it) {
        if (tid == 0) n_unm = 0;
        __syncthreads();
        if (tid < G_ && col_cnt[tid] == 0) {
            const int pidx = atomicAdd(&n_unm, 1);
            unm_list[pidx] = tid;
        }
        __syncthreads();
        const int nu = n_unm;
        if (nu == 0) break;

        for (int q = tid; q < Q_; q += 256) {
            if (rmatch[q] >= 0) addv[q] += 100000.f;
            newh[q] = 0;
        }
        __syncthreads();

        // per-unmatched-column argmin_q over coalesced costT columns
        const int wv = tid >> 6, ln = tid & 63;
        for (int u = wv; u < nu; u += 4) {
            const int gg = unm_list[u];
            const float4* col = (const float4*)(ctb + (size_t)gg * Q_);
            float bv = 1e38f; int bq = 0x7fffffff;
            for (int s = 0; s < Q_ / 256; ++s) {
                const int qb = s * 256 + ln * 4;
                const float4 c4 = col[qb >> 2];
                const float4 a4 = *(const float4*)&addv[qb];
                const float v0 = c4.x + a4.x, v1 = c4.y + a4.y;
                const float v2 = c4.z + a4.z, v3 = c4.w + a4.w;
                if (v0 < bv || (v0 == bv && qb     < bq)) { bv = v0; bq = qb; }
                if (v1 < bv || (v1 == bv && qb + 1 < bq)) { bv = v1; bq = qb + 1; }
                if (v2 < bv || (v2 == bv && qb + 2 < bq)) { bv = v2; bq = qb + 2; }
                if (v3 < bv || (v3 == bv && qb + 3 < bq)) { bv = v3; bq = qb + 3; }
            }
            for (int off = 32; off > 0; off >>= 1) {
                const float ov = __shfl_xor(bv, off);
                const int   oq = __shfl_xor(bq, off);
                if (ov < bv || (ov == bv && oq < bq)) { bv = ov; bq = oq; }
            }
            if (ln == 0) amin_q[u] = bq;
        }
        __syncthreads();

        if (tid < nu) {
            const int q = amin_q[tid];
            atomicAdd(&newh[q], 1);
            newg[q] = (unsigned char)unm_list[tid];  // only read when nh==1
        }
        __syncthreads();

        for (int q = tid; q < Q_; q += 256) {
            const int nh = newh[q];
            if (nh > 0) {
                const int total = nh + (rmatch[q] >= 0 ? 1 : 0);
                rmatch[q] = (total == 1) ? (short)newg[q] : (short)s_ra[q];
            }
        }
        __syncthreads();
        if (tid < G_) col_cnt[tid] = 0;
        __syncthreads();
        for (int q = tid; q < Q_; q += 256)
            if (rmatch[q] >= 0) atomicAdd(&col_cnt[rmatch[q]], 1);
        __syncthreads();
    }

    for (int q = tid; q < Q_; q += 256)
        rmatch_final[b * Q_ + q] = rmatch[q];
}

// ---------------------------------------------------------------------------
// Kernel D: expand rmatch -> full match plane (fully parallel float4 writes).
// ---------------------------------------------------------------------------
__global__ __launch_bounds__(256) void expand_kernel(
    const int* __restrict__ rmatch_final, float* __restrict__ out_match)
{
    const int idx = blockIdx.x * 256 + threadIdx.x;  // float4 index
    const int row = idx >> 5;                        // G/4 = 32 float4 per row
    const int gb  = (idx & 31) << 2;
    const int rm  = rmatch_final[row];
    float4 o;
    o.x = (rm == gb)     ? 1.f : 0.f;
    o.y = (rm == gb + 1) ? 1.f : 0.f;
    o.z = (rm == gb + 2) ? 1.f : 0.f;
    o.w = (rm == gb + 3) ? 1.f : 0.f;
    ((float4*)out_match)[idx] = o;
}

extern "C" void kernel_launch(void* const* d_in, const int* in_sizes, int n_in,
                              void* d_out, int out_size, void* d_ws, size_t ws_size,
                              hipStream_t stream) {
    const float* logits  = (const float*)d_in[0];
    const float* pboxes  = (const float*)d_in[1];
    const float* gboxes  = (const float*)d_in[2];
    const int*   glabels = (const int*)d_in[3];

    float* out = (float*)d_out;
    const size_t BQG = (size_t)B_ * Q_ * G_;
    float* out_match = out;
    float* out_cost  = out + BQG;
    float* out_iou   = out + 2 * BQG;

    // workspace layout (~40.5 MB)
    char* ws = (char*)d_ws;
    size_t off = 0;
    float* costT = (float*)(ws + off); off += (size_t)B_ * G_ * Q_ * 4;
    float* piou  = (float*)(ws + off); off += (size_t)B_ * G_ * NCH * 10 * 4;
    float* pcv   = (float*)(ws + off); off += (size_t)B_ * G_ * NCH * 10 * 4;
    int*   pcq   = (int*)  (ws + off); off += (size_t)B_ * G_ * NCH * 10 * 4;
    int*   ramin = (int*)  (ws + off); off += (size_t)B_ * Q_ * 4;
    int*   cnt   = (int*)  (ws + off); off += (size_t)B_ * Q_ * 4;
    int*   gsel  = (int*)  (ws + off); off += (size_t)B_ * Q_ * 4;
    int*   rmf   = (int*)  (ws + off); off += (size_t)B_ * Q_ * 4;

    hipMemsetAsync(cnt, 0, (size_t)B_ * Q_ * 4, stream);
    fused_cost_kernel<<<dim3(NCH, B_), 256, 0, stream>>>(
        logits, pboxes, gboxes, glabels, out_cost, out_iou, costT, piou, pcv, pcq);
    ramin_kernel<<<B_ * Q_ / 4, 256, 0, stream>>>(out_cost, ramin);
    dynk_scatter_kernel<<<B_, 128, 0, stream>>>(piou, pcv, pcq, cnt, gsel);
    loop_kernel<<<B_, 256, 0, stream>>>(costT, cnt, gsel, ramin, rmf);
    expand_kernel<<<(int)(BQG / 4 / 256), 256, 0, stream>>>(rmf, out_match);
}

// Round 3
// 261.658 us; speedup vs baseline: 2.3080x; 1.4598x over previous
//
#include <hip/hip_runtime.h>
#include <cstdint>
#include <cstddef>

#define B_ 16
#define Q_ 4096
#define G_ 128
#define C_ 80
#define QCHUNK 128
#define NCH (Q_ / QCHUNK)   // 32 chunks

__device__ __forceinline__ bool lexless(float v1, int q1, float v2, int q2) {
    return v1 < v2 || (v1 == v2 && q1 < q2);
}

// pack (cost,q) into a sortable u64 key: asc key order == lex (cost asc, q asc)
__device__ __forceinline__ unsigned long long packkey(float v, int q) {
    unsigned int bts = __float_as_uint(v);
    if (bts == 0x80000000u) bts = 0u;  // -0.0 -> +0.0 (equal as floats)
    bts = (bts & 0x80000000u) ? ~bts : (bts | 0x80000000u);
    return ((unsigned long long)bts << 32) | (unsigned int)q;
}

// merge two desc-sorted 5-lists -> top-5 desc (branchless network)
__device__ __forceinline__ void merge5_desc(
    float& a0, float& a1, float& a2, float& a3, float& a4,
    float b0, float b1, float b2, float b3, float b4)
{
    const float r0 = fmaxf(a0, b0);
    const float r1 = fmaxf(fmaxf(a1, b1), fminf(a0, b0));
    const float r2 = fmaxf(fmaxf(a2, b2), fmaxf(fminf(a0, b1), fminf(a1, b0)));
    const float r3 = fmaxf(fmaxf(a3, b3),
                     fmaxf(fminf(a0, b2), fmaxf(fminf(a1, b1), fminf(a2, b0))));
    const float r4 = fmaxf(fmaxf(a4, b4),
                     fmaxf(fmaxf(fminf(a0, b3), fminf(a3, b0)),
                           fmaxf(fminf(a1, b2), fminf(a2, b1))));
    a0 = r0; a1 = r1; a2 = r2; a3 = r3; a4 = r4;
}

__device__ __forceinline__ unsigned long long umin64(unsigned long long a, unsigned long long b) { return a < b ? a : b; }
__device__ __forceinline__ unsigned long long umax64(unsigned long long a, unsigned long long b) { return a > b ? a : b; }

// merge two asc-sorted 5-lists of u64 keys -> bottom-5 asc
__device__ __forceinline__ void merge5_asc(
    unsigned long long& a0, unsigned long long& a1, unsigned long long& a2,
    unsigned long long& a3, unsigned long long& a4,
    unsigned long long b0, unsigned long long b1, unsigned long long b2,
    unsigned long long b3, unsigned long long b4)
{
    const unsigned long long r0 = umin64(a0, b0);
    const unsigned long long r1 = umin64(umin64(a1, b1), umax64(a0, b0));
    const unsigned long long r2 = umin64(umin64(a2, b2), umin64(umax64(a0, b1), umax64(a1, b0)));
    const unsigned long long r3 = umin64(umin64(a3, b3),
                                  umin64(umax64(a0, b2), umin64(umax64(a1, b1), umax64(a2, b0))));
    const unsigned long long r4 = umin64(umin64(a4, b4),
                                  umin64(umin64(umax64(a0, b3), umax64(a3, b0)),
                                         umin64(umax64(a1, b2), umax64(a2, b1))));
    a0 = r0; a1 = r1; a2 = r2; a3 = r3; a4 = r4;
}

// ---------------------------------------------------------------------------
// Kernel A: fused cost/iou + per-chunk partial top5(iou) / bottom5(cost,q).
// Block = (chunk of 128 q's, batch). Thread: g = tid&127, qh = tid>>7.
// Writes: out_cost, out_iou (B,Q,G), costT (B,G,Q), partials (B,G,NCH,2,5).
// ---------------------------------------------------------------------------
__global__ __launch_bounds__(256) void fused_cost_kernel(
    const float* __restrict__ logits,
    const float* __restrict__ pboxes,
    const float* __restrict__ gboxes,
    const int*   __restrict__ glabels,
    float* __restrict__ out_cost,
    float* __restrict__ out_iou,
    float* __restrict__ costT,
    float* __restrict__ piou,
    float* __restrict__ pcv,
    int*   __restrict__ pcq)
{
    const int tid = threadIdx.x;
    const int g   = tid & 127;
    const int qh  = tid >> 7;
    const int ci  = blockIdx.x, b = blockIdx.y;
    const int q0  = ci * QCHUNK;

    __shared__ float pq[QCHUNK][16];   // 8 corners + derived per q
    __shared__ int   fgf[QCHUNK];
    __shared__ float lbuf[16 * 80];    // logits for 16 staged q's

    // ---- per-thread gt constants ----
    const float4* gb4 = (const float4*)(gboxes + ((size_t)b * G_ + g) * 8);
    const float4 gA = gb4[0], gB = gb4[1];
    const float g0 = gA.x, g1 = gA.y, g2 = gA.z, g3 = gA.w;
    const float g4 = gB.x, g5 = gB.y, g6 = gB.z, g7 = gB.w;
    const float gxc = (g0 + g2 + g4 + g6) * 0.25f;
    const float gyc = (g1 + g3 + g5 + g7) * 0.25f;
    const float gw = sqrtf((g0 - g2) * (g0 - g2) + (g1 - g3) * (g1 - g3));
    const float gh = sqrtf((g2 - g4) * (g2 - g4) + (g3 - g5) * (g3 - g5));
    const float gax0 = gxc - gw * 0.5f, gay0 = gyc - gh * 0.5f;
    const float gax1 = gxc + gw * 0.5f, gay1 = gyc + gh * 0.5f;
    const float garea = (gax1 - gax0) * (gay1 - gay0);
    const float v1x = g2 - g0, v1y = g3 - g1, v2x = g4 - g0, v2y = g5 - g1;
    const float gt_area = fabsf(v1x * v2y - v1y * v2x) * 0.5f;
    const float mxx = fmaxf(fmaxf(g0, g2), fmaxf(g4, g6));
    const float mnx = fminf(fminf(g0, g2), fminf(g4, g6));
    const float mxy = fmaxf(fmaxf(g1, g3), fmaxf(g5, g7));
    const float mny = fminf(fminf(g1, g3), fminf(g5, g7));
    const float dgx = mxx - mnx, dgy = mxy - mny;
    const float radius = sqrtf(dgx * dgx + dgy * dgy) / 32.0f;
    const float thresh = gt_area / radius;
    const int lab = glabels[b * G_ + g];

    // ---- stage pred boxes for this chunk (coalesced float4) ----
    {
        const float4 v = ((const float4*)(pboxes + ((size_t)b * Q_ + q0) * 8))[tid];
        *(float4*)&pq[tid >> 1][(tid & 1) * 4] = v;
    }
    __syncthreads();
    if (tid < QCHUNK) {
        const float* pr = pq[tid];
        const float p0 = pr[0], p1 = pr[1], p2 = pr[2], p3 = pr[3];
        const float p4 = pr[4], p5v = pr[5], p6 = pr[6], p7 = pr[7];
        const float pxc = (p0 + p2 + p4 + p6) * 0.25f;
        const float pyc = (p1 + p3 + p5v + p7) * 0.25f;
        const float pw = sqrtf((p0 - p2) * (p0 - p2) + (p1 - p3) * (p1 - p3));
        const float ph = sqrtf((p2 - p4) * (p2 - p4) + (p3 - p5v) * (p3 - p5v));
        pq[tid][8]  = pxc;
        pq[tid][9]  = pyc;
        pq[tid][10] = pxc - pw * 0.5f;
        pq[tid][11] = pyc - ph * 0.5f;
        pq[tid][12] = pxc + pw * 0.5f;
        pq[tid][13] = pyc + ph * 0.5f;
        pq[tid][14] = pw * ph;
        fgf[tid] = 0;
    }
    __syncthreads();

    // ---- pass 1: fg mask (any over g) ----
    const int lane0 = ((tid & 63) == 0);
    for (int i = 0; i < QCHUNK / 2; ++i) {
        const int ql = 2 * i + qh;
        const float dx = pq[ql][8] - gxc, dy = pq[ql][9] - gyc;
        const int in = sqrtf(dx * dx + dy * dy) <= thresh;
        const int anyin = __any(in);
        if (anyin && lane0) fgf[ql] = 1;
    }

    // ---- pass 2: full cost + running top5/bot5 ----
    float t0 = -1e38f, t1 = -1e38f, t2 = -1e38f, t3 = -1e38f, t4 = -1e38f;
    float c0v = 1e38f, c1v = 1e38f, c2v = 1e38f, c3v = 1e38f, c4v = 1e38f;
    int   c0q = 0x7fffffff, c1q = 0x7fffffff, c2q = 0x7fffffff,
          c3q = 0x7fffffff, c4q = 0x7fffffff;

    for (int sc = 0; sc < QCHUNK / 16; ++sc) {
        __syncthreads();  // also covers fgf hazard on sc==0
        for (int j = tid; j < 16 * 80; j += 256)
            lbuf[j] = logits[((size_t)b * Q_ + q0 + sc * 16) * 80 + j];
        __syncthreads();
        for (int jj = 0; jj < 8; ++jj) {
            const int ql = sc * 16 + 2 * jj + qh;
            const int q  = q0 + ql;
            const float* pr = pq[ql];
            const float p0 = pr[0], p1 = pr[1], p2 = pr[2], p3 = pr[3];
            const float p4 = pr[4], p5v = pr[5], p6 = pr[6], p7 = pr[7];
            const float pxc = pr[8], pyc = pr[9];
            const float pax0 = pr[10], pay0 = pr[11], pax1 = pr[12], pay1 = pr[13];
            const float parea = pr[14];

            const float l1 = fabsf(p0 - g0) + fabsf(p1 - g1) + fabsf(p2 - g2)
                           + fabsf(p3 - g3) + fabsf(p4 - g4) + fabsf(p5v - g5)
                           + fabsf(p6 - g6) + fabsf(p7 - g7);

            const float ltx = fmaxf(pax0, gax0), lty = fmaxf(pay0, gay0);
            const float rbx = fminf(pax1, gax1), rby = fminf(pay1, gay1);
            const float iw = fmaxf(rbx - ltx, 0.f), ih = fmaxf(rby - lty, 0.f);
            const float inter = iw * ih;
            const float iou = inter / (parea + garea - inter + 1e-8f);

            const float ew = fmaxf(pax1, gax1) - fminf(pax0, gax0);
            const float eh = fmaxf(pay1, gay1) - fminf(pay0, gay0);
            const float cc2 = ew * ew + eh * eh + 1e-8f;
            const float dx = pxc - gxc, dy = pyc - gyc;
            const float diou = iou - (dx * dx + dy * dy) / cc2;

            const float x = lbuf[(2 * jj + qh) * 80 + lab];
            float p;
            if (x >= 0.f) { const float e = expf(-x); p = 1.f / (1.f + e); }
            else          { const float e = expf(x);  p = e / (1.f + e); }
            const float pos = 0.25f * (1.f - p) * (1.f - p) * (-logf(p + 1e-8f));
            const float neg = 0.75f * p * p * (-logf(1.f - p + 1e-8f));
            const float cclass = pos - neg;

            const float cost = 5.f * l1 + 2.f * cclass + 2.f * diou
                             + (fgf[ql] ? 0.f : 10000.f);

            const size_t o = ((size_t)b * Q_ + q) * G_ + g;
            out_cost[o] = cost;
            out_iou[o]  = iou;
            costT[((size_t)b * G_ + g) * Q_ + q] = cost;

            if (iou > t4) {
                if (iou > t0)      { t4 = t3; t3 = t2; t2 = t1; t1 = t0; t0 = iou; }
                else if (iou > t1) { t4 = t3; t3 = t2; t2 = t1; t1 = iou; }
                else if (iou > t2) { t4 = t3; t3 = t2; t2 = iou; }
                else if (iou > t3) { t4 = t3; t3 = iou; }
                else               { t4 = iou; }
            }
            if (lexless(cost, q, c4v, c4q)) {
                if (lexless(cost, q, c0v, c0q)) {
                    c4v = c3v; c4q = c3q; c3v = c2v; c3q = c2q; c2v = c1v; c2q = c1q;
                    c1v = c0v; c1q = c0q; c0v = cost; c0q = q;
                } else if (lexless(cost, q, c1v, c1q)) {
                    c4v = c3v; c4q = c3q; c3v = c2v; c3q = c2q; c2v = c1v; c2q = c1q;
                    c1v = cost; c1q = q;
                } else if (lexless(cost, q, c2v, c2q)) {
                    c4v = c3v; c4q = c3q; c3v = c2v; c3q = c2q; c2v = cost; c2q = q;
                } else if (lexless(cost, q, c3v, c3q)) {
                    c4v = c3v; c4q = c3q; c3v = cost; c3q = q;
                } else { c4v = cost; c4q = q; }
            }
        }
    }

    // ---- write partials: [B][G][NCH][2][5] ----
    const size_t pbase = (((size_t)b * G_ + g) * NCH + ci) * 10 + qh * 5;
    piou[pbase + 0] = t0; piou[pbase + 1] = t1; piou[pbase + 2] = t2;
    piou[pbase + 3] = t3; piou[pbase + 4] = t4;
    pcv[pbase + 0] = c0v; pcv[pbase + 1] = c1v; pcv[pbase + 2] = c2v;
    pcv[pbase + 3] = c3v; pcv[pbase + 4] = c4v;
    pcq[pbase + 0] = c0q; pcq[pbase + 1] = c1q; pcq[pbase + 2] = c2q;
    pcq[pbase + 3] = c3q; pcq[pbase + 4] = c4q;
}

// ---------------------------------------------------------------------------
// Kernel E: row argmin of cost (first-index tie-break).  One wave per row.
// ---------------------------------------------------------------------------
__global__ __launch_bounds__(256) void ramin_kernel(
    const float* __restrict__ cost, int* __restrict__ ramin)
{
    const int wv = threadIdx.x >> 6, ln = threadIdx.x & 63;
    const int row = blockIdx.x * 4 + wv;  // row in [0, B*Q)
    const float2 c2v = ((const float2*)(cost + (size_t)row * G_))[ln];
    float v; int gg;
    if (c2v.x <= c2v.y) { v = c2v.x; gg = 2 * ln; }
    else                { v = c2v.y; gg = 2 * ln + 1; }
    for (int off = 32; off > 0; off >>= 1) {
        const float ov = __shfl_xor(v, off);
        const int   og = __shfl_xor(gg, off);
        if (ov < v || (ov == v && og < gg)) { v = ov; gg = og; }
    }
    if (ln == 0) ramin[row] = gg;
}

// ---------------------------------------------------------------------------
// Kernel B: per (b,g) column merge of 64 sorted 5-lists via wave butterfly.
// One wave per column; branchless min/max merge networks; u64 keys carry q.
// ---------------------------------------------------------------------------
__global__ __launch_bounds__(256) void dynk_scatter_kernel(
    const float* __restrict__ piou,
    const float* __restrict__ pcv,
    const int*   __restrict__ pcq,
    int* __restrict__ cnt,
    int* __restrict__ gsel)
{
    const int wv = threadIdx.x >> 6, ln = threadIdx.x & 63;
    const int col = blockIdx.x * 4 + wv;   // col in [0, B_*G_)
    const int b = col >> 7, g = col & 127;
    const size_t base = (size_t)col * (NCH * 10) + (size_t)ln * 5;

    float t0 = piou[base + 0], t1 = piou[base + 1], t2 = piou[base + 2],
          t3 = piou[base + 3], t4 = piou[base + 4];
    unsigned long long k0 = packkey(pcv[base + 0], pcq[base + 0]);
    unsigned long long k1 = packkey(pcv[base + 1], pcq[base + 1]);
    unsigned long long k2 = packkey(pcv[base + 2], pcq[base + 2]);
    unsigned long long k3 = packkey(pcv[base + 3], pcq[base + 3]);
    unsigned long long k4 = packkey(pcv[base + 4], pcq[base + 4]);

    #pragma unroll
    for (int off = 1; off < 64; off <<= 1) {
        merge5_desc(t0, t1, t2, t3, t4,
                    __shfl_xor(t0, off), __shfl_xor(t1, off), __shfl_xor(t2, off),
                    __shfl_xor(t3, off), __shfl_xor(t4, off));
        merge5_asc(k0, k1, k2, k3, k4,
                   __shfl_xor(k0, off), __shfl_xor(k1, off), __shfl_xor(k2, off),
                   __shfl_xor(k3, off), __shfl_xor(k4, off));
    }

    if (ln == 0) {
        const float s = t0 + t1 + t2 + t3 + t4;
        int dynk = (int)s;
        if (dynk < 1) dynk = 1;
        if (dynk > 5) dynk = 5;
        const unsigned long long ks[5] = {k0, k1, k2, k3, k4};
        #pragma unroll
        for (int i = 0; i < 5; ++i) {
            if (i < dynk) {
                const int q = (int)(ks[i] & 0xffffffffu);
                atomicAdd(&cnt[b * Q_ + q], 1);
                gsel[b * Q_ + q] = g;   // only read when cnt==1 (single writer)
            }
        }
    }
}

// ---------------------------------------------------------------------------
// Kernel C: per-batch sequential refinement loop (LDS state, costT columns).
// ---------------------------------------------------------------------------
__global__ __launch_bounds__(256) void loop_kernel(
    const float* __restrict__ costT,
    const int* __restrict__ cnt,
    const int* __restrict__ gsel,
    const int* __restrict__ ramin,
    int* __restrict__ rmatch_final)
{
    const int b = blockIdx.x, tid = threadIdx.x;
    const float* ctb = costT + (size_t)b * G_ * Q_;

    __shared__ short rmatch[Q_];
    __shared__ __align__(16) float addv[Q_];
    __shared__ unsigned char s_ra[Q_];
    __shared__ unsigned char newg[Q_];
    __shared__ int newh[Q_];
    __shared__ int col_cnt[G_];
    __shared__ int unm_list[G_];
    __shared__ int amin_q[G_];
    __shared__ int n_unm;

    for (int q = tid; q < Q_; q += 256) {
        const int c  = cnt[b * Q_ + q];
        const int ra = ramin[b * Q_ + q];
        s_ra[q] = (unsigned char)ra;
        addv[q] = 0.f;
        rmatch[q] = (c == 0) ? (short)-1
                             : (c == 1 ? (short)gsel[b * Q_ + q] : (short)ra);
    }
    __syncthreads();
    if (tid < G_) col_cnt[tid] = 0;
    __syncthreads();
    for (int q = tid; q < Q_; q += 256)
        if (rmatch[q] >= 0) atomicAdd(&col_cnt[rmatch[q]], 1);
    __syncthreads();

    for (int it = 0; it < G_; ++it) {
        if (tid == 0) n_unm = 0;
        __syncthreads();
        if (tid < G_ && col_cnt[tid] == 0) {
            const int pidx = atomicAdd(&n_unm, 1);
            unm_list[pidx] = tid;
        }
        __syncthreads();
        const int nu = n_unm;
        if (nu == 0) break;

        for (int q = tid; q < Q_; q += 256) {
            if (rmatch[q] >= 0) addv[q] += 100000.f;
            newh[q] = 0;
        }
        __syncthreads();

        const int wv = tid >> 6, ln = tid & 63;
        for (int u = wv; u < nu; u += 4) {
            const int gg = unm_list[u];
            const float4* col = (const float4*)(ctb + (size_t)gg * Q_);
            float bv = 1e38f; int bq = 0x7fffffff;
            for (int s = 0; s < Q_ / 256; ++s) {
                const int qb = s * 256 + ln * 4;
                const float4 c4 = col[qb >> 2];
                const float4 a4 = *(const float4*)&addv[qb];
                const float v0 = c4.x + a4.x, v1 = c4.y + a4.y;
                const float v2 = c4.z + a4.z, v3 = c4.w + a4.w;
                if (v0 < bv || (v0 == bv && qb     < bq)) { bv = v0; bq = qb; }
                if (v1 < bv || (v1 == bv && qb + 1 < bq)) { bv = v1; bq = qb + 1; }
                if (v2 < bv || (v2 == bv && qb + 2 < bq)) { bv = v2; bq = qb + 2; }
                if (v3 < bv || (v3 == bv && qb + 3 < bq)) { bv = v3; bq = qb + 3; }
            }
            for (int off = 32; off > 0; off >>= 1) {
                const float ov = __shfl_xor(bv, off);
                const int   oq = __shfl_xor(bq, off);
                if (ov < bv || (ov == bv && oq < bq)) { bv = ov; bq = oq; }
            }
            if (ln == 0) amin_q[u] = bq;
        }
        __syncthreads();

        if (tid < nu) {
            const int q = amin_q[tid];
            atomicAdd(&newh[q], 1);
            newg[q] = (unsigned char)unm_list[tid];  // only read when nh==1
        }
        __syncthreads();

        for (int q = tid; q < Q_; q += 256) {
            const int nh = newh[q];
            if (nh > 0) {
                const int total = nh + (rmatch[q] >= 0 ? 1 : 0);
                rmatch[q] = (total == 1) ? (short)newg[q] : (short)s_ra[q];
            }
        }
        __syncthreads();
        if (tid < G_) col_cnt[tid] = 0;
        __syncthreads();
        for (int q = tid; q < Q_; q += 256)
            if (rmatch[q] >= 0) atomicAdd(&col_cnt[rmatch[q]], 1);
        __syncthreads();
    }

    for (int q = tid; q < Q_; q += 256)
        rmatch_final[b * Q_ + q] = rmatch[q];
}

// ---------------------------------------------------------------------------
// Kernel D: expand rmatch -> full match plane (fully parallel float4 writes).
// ---------------------------------------------------------------------------
__global__ __launch_bounds__(256) void expand_kernel(
    const int* __restrict__ rmatch_final, float* __restrict__ out_match)
{
    const int idx = blockIdx.x * 256 + threadIdx.x;  // float4 index
    const int row = idx >> 5;                        // G/4 = 32 float4 per row
    const int gb  = (idx & 31) << 2;
    const int rm  = rmatch_final[row];
    float4 o;
    o.x = (rm == gb)     ? 1.f : 0.f;
    o.y = (rm == gb + 1) ? 1.f : 0.f;
    o.z = (rm == gb + 2) ? 1.f : 0.f;
    o.w = (rm == gb + 3) ? 1.f : 0.f;
    ((float4*)out_match)[idx] = o;
}

extern "C" void kernel_launch(void* const* d_in, const int* in_sizes, int n_in,
                              void* d_out, int out_size, void* d_ws, size_t ws_size,
                              hipStream_t stream) {
    const float* logits  = (const float*)d_in[0];
    const float* pboxes  = (const float*)d_in[1];
    const float* gboxes  = (const float*)d_in[2];
    const int*   glabels = (const int*)d_in[3];

    float* out = (float*)d_out;
    const size_t BQG = (size_t)B_ * Q_ * G_;
    float* out_match = out;
    float* out_cost  = out + BQG;
    float* out_iou   = out + 2 * BQG;

    // workspace layout (~40.5 MB)
    char* ws = (char*)d_ws;
    size_t off = 0;
    float* costT = (float*)(ws + off); off += (size_t)B_ * G_ * Q_ * 4;
    float* piou  = (float*)(ws + off); off += (size_t)B_ * G_ * NCH * 10 * 4;
    float* pcv   = (float*)(ws + off); off += (size_t)B_ * G_ * NCH * 10 * 4;
    int*   pcq   = (int*)  (ws + off); off += (size_t)B_ * G_ * NCH * 10 * 4;
    int*   ramin = (int*)  (ws + off); off += (size_t)B_ * Q_ * 4;
    int*   cnt   = (int*)  (ws + off); off += (size_t)B_ * Q_ * 4;
    int*   gsel  = (int*)  (ws + off); off += (size_t)B_ * Q_ * 4;
    int*   rmf   = (int*)  (ws + off); off += (size_t)B_ * Q_ * 4;

    hipMemsetAsync(cnt, 0, (size_t)B_ * Q_ * 4, stream);
    fused_cost_kernel<<<dim3(NCH, B_), 256, 0, stream>>>(
        logits, pboxes, gboxes, glabels, out_cost, out_iou, costT, piou, pcv, pcq);
    ramin_kernel<<<B_ * Q_ / 4, 256, 0, stream>>>(out_cost, ramin);
    dynk_scatter_kernel<<<B_ * G_ / 4, 256, 0, stream>>>(piou, pcv, pcq, cnt, gsel);
    loop_kernel<<<B_, 256, 0, stream>>>(costT, cnt, gsel, ramin, rmf);
    expand_kernel<<<(int)(BQG / 4 / 256), 256, 0, stream>>>(rmf, out_match);
}

// Round 4
// 239.503 us; speedup vs baseline: 2.5215x; 1.0925x over previous
//
#include <hip/hip_runtime.h>
#include <cstdint>
#include <cstddef>

#define B_ 16
#define Q_ 4096
#define G_ 128
#define C_ 80
#define QCHUNK 64
#define NCH (Q_ / QCHUNK)   // 64 chunks

typedef unsigned long long u64;
#define U64MAX 0xffffffffffffffffull

// pack (cost,q) into a sortable u64 key: asc key order == lex (cost asc, q asc)
__device__ __forceinline__ u64 packkey(float v, int q) {
    unsigned int bts = __float_as_uint(v);
    if (bts == 0x80000000u) bts = 0u;  // -0.0 -> +0.0
    bts = (bts & 0x80000000u) ? ~bts : (bts | 0x80000000u);
    return ((u64)bts << 32) | (unsigned int)q;
}

__device__ __forceinline__ u64 umin64(u64 a, u64 b) { return a < b ? a : b; }
__device__ __forceinline__ u64 umax64(u64 a, u64 b) { return a > b ? a : b; }

// merge two desc-sorted 5-lists -> top-5 desc (branchless network)
__device__ __forceinline__ void merge5_desc(
    float& a0, float& a1, float& a2, float& a3, float& a4,
    float b0, float b1, float b2, float b3, float b4)
{
    const float r0 = fmaxf(a0, b0);
    const float r1 = fmaxf(fmaxf(a1, b1), fminf(a0, b0));
    const float r2 = fmaxf(fmaxf(a2, b2), fmaxf(fminf(a0, b1), fminf(a1, b0)));
    const float r3 = fmaxf(fmaxf(a3, b3),
                     fmaxf(fminf(a0, b2), fmaxf(fminf(a1, b1), fminf(a2, b0))));
    const float r4 = fmaxf(fmaxf(a4, b4),
                     fmaxf(fmaxf(fminf(a0, b3), fminf(a3, b0)),
                           fmaxf(fminf(a1, b2), fminf(a2, b1))));
    a0 = r0; a1 = r1; a2 = r2; a3 = r3; a4 = r4;
}

// merge two asc-sorted 5-lists of u64 keys -> bottom-5 asc
__device__ __forceinline__ void merge5_asc(
    u64& a0, u64& a1, u64& a2, u64& a3, u64& a4,
    u64 b0, u64 b1, u64 b2, u64 b3, u64 b4)
{
    const u64 r0 = umin64(a0, b0);
    const u64 r1 = umin64(umin64(a1, b1), umax64(a0, b0));
    const u64 r2 = umin64(umin64(a2, b2), umin64(umax64(a0, b1), umax64(a1, b0)));
    const u64 r3 = umin64(umin64(a3, b3),
                   umin64(umax64(a0, b2), umin64(umax64(a1, b1), umax64(a2, b0))));
    const u64 r4 = umin64(umin64(a4, b4),
                   umin64(umin64(umax64(a0, b3), umax64(a3, b0)),
                          umin64(umax64(a1, b2), umax64(a2, b1))));
    a0 = r0; a1 = r1; a2 = r2; a3 = r3; a4 = r4;
}

// ---------------------------------------------------------------------------
// Kernel P: focal class cost table posneg[B][Q][C] (elementwise, coalesced).
// ---------------------------------------------------------------------------
__global__ __launch_bounds__(256) void posneg_kernel(
    const float* __restrict__ logits, float* __restrict__ posneg)
{
    const int i = blockIdx.x * 256 + threadIdx.x;
    const float x = logits[i];
    float p;
    if (x >= 0.f) { const float e = expf(-x); p = 1.f / (1.f + e); }
    else          { const float e = expf(x);  p = e / (1.f + e); }
    const float pos = 0.25f * (1.f - p) * (1.f - p) * (-logf(p + 1e-8f));
    const float neg = 0.75f * p * p * (-logf(1.f - p + 1e-8f));
    posneg[i] = pos - neg;
}

// ---------------------------------------------------------------------------
// Kernel A: fused cost/iou + per-chunk top-5 iou partials.
// Block = (chunk of 64 q's, batch). Thread: g = tid&127, qh = tid>>7.
// ---------------------------------------------------------------------------
__global__ __launch_bounds__(256) void fused_cost_kernel(
    const float* __restrict__ posneg,
    const float* __restrict__ pboxes,
    const float* __restrict__ gboxes,
    const int*   __restrict__ glabels,
    float* __restrict__ out_cost,
    float* __restrict__ out_iou,
    float* __restrict__ costT,
    float* __restrict__ piou)
{
    const int tid = threadIdx.x;
    const int g   = tid & 127;
    const int qh  = tid >> 7;
    const int ci  = blockIdx.x, b = blockIdx.y;
    const int q0  = ci * QCHUNK;

    __shared__ float pq[QCHUNK][16];
    __shared__ int   fgf[QCHUNK];
    __shared__ float lbuf[16 * 80];

    // ---- per-thread gt constants ----
    const float4* gb4 = (const float4*)(gboxes + ((size_t)b * G_ + g) * 8);
    const float4 gA = gb4[0], gB = gb4[1];
    const float g0 = gA.x, g1 = gA.y, g2 = gA.z, g3 = gA.w;
    const float g4 = gB.x, g5 = gB.y, g6 = gB.z, g7 = gB.w;
    const float gxc = (g0 + g2 + g4 + g6) * 0.25f;
    const float gyc = (g1 + g3 + g5 + g7) * 0.25f;
    const float gw = sqrtf((g0 - g2) * (g0 - g2) + (g1 - g3) * (g1 - g3));
    const float gh = sqrtf((g2 - g4) * (g2 - g4) + (g3 - g5) * (g3 - g5));
    const float gax0 = gxc - gw * 0.5f, gay0 = gyc - gh * 0.5f;
    const float gax1 = gxc + gw * 0.5f, gay1 = gyc + gh * 0.5f;
    const float garea = (gax1 - gax0) * (gay1 - gay0);
    const float v1x = g2 - g0, v1y = g3 - g1, v2x = g4 - g0, v2y = g5 - g1;
    const float gt_area = fabsf(v1x * v2y - v1y * v2x) * 0.5f;
    const float mxx = fmaxf(fmaxf(g0, g2), fmaxf(g4, g6));
    const float mnx = fminf(fminf(g0, g2), fminf(g4, g6));
    const float mxy = fmaxf(fmaxf(g1, g3), fmaxf(g5, g7));
    const float mny = fminf(fminf(g1, g3), fminf(g5, g7));
    const float dgx = mxx - mnx, dgy = mxy - mny;
    const float radius = sqrtf(dgx * dgx + dgy * dgy) / 32.0f;
    const float thresh = gt_area / radius;
    const int lab = glabels[b * G_ + g];

    // ---- stage pred boxes (64 q x 8 floats = 128 float4) ----
    if (tid < 128) {
        const float4 v = ((const float4*)(pboxes + ((size_t)b * Q_ + q0) * 8))[tid];
        *(float4*)&pq[tid >> 1][(tid & 1) * 4] = v;
    }
    __syncthreads();
    if (tid < QCHUNK) {
        const float* pr = pq[tid];
        const float p0 = pr[0], p1 = pr[1], p2 = pr[2], p3 = pr[3];
        const float p4 = pr[4], p5v = pr[5], p6 = pr[6], p7 = pr[7];
        const float pxc = (p0 + p2 + p4 + p6) * 0.25f;
        const float pyc = (p1 + p3 + p5v + p7) * 0.25f;
        const float pw = sqrtf((p0 - p2) * (p0 - p2) + (p1 - p3) * (p1 - p3));
        const float ph = sqrtf((p2 - p4) * (p2 - p4) + (p3 - p5v) * (p3 - p5v));
        pq[tid][8]  = pxc;
        pq[tid][9]  = pyc;
        pq[tid][10] = pxc - pw * 0.5f;
        pq[tid][11] = pyc - ph * 0.5f;
        pq[tid][12] = pxc + pw * 0.5f;
        pq[tid][13] = pyc + ph * 0.5f;
        pq[tid][14] = pw * ph;
        fgf[tid] = 0;
    }
    __syncthreads();

    // ---- pass 1: fg mask (any over g) ----
    const int lane0 = ((tid & 63) == 0);
    for (int i = 0; i < QCHUNK / 2; ++i) {
        const int ql = 2 * i + qh;
        const float dx = pq[ql][8] - gxc, dy = pq[ql][9] - gyc;
        const int in = sqrtf(dx * dx + dy * dy) <= thresh;
        const int anyin = __any(in);
        if (anyin && lane0) fgf[ql] = 1;
    }

    // ---- pass 2: full cost + running top-5 iou ----
    float t0 = -1e38f, t1 = -1e38f, t2 = -1e38f, t3 = -1e38f, t4 = -1e38f;

    for (int sc = 0; sc < QCHUNK / 16; ++sc) {
        __syncthreads();  // also covers fgf hazard on sc==0
        for (int j = tid; j < 16 * 80; j += 256)
            lbuf[j] = posneg[((size_t)b * Q_ + q0 + sc * 16) * 80 + j];
        __syncthreads();
        #pragma unroll
        for (int jj = 0; jj < 8; ++jj) {
            const int ql = sc * 16 + 2 * jj + qh;
            const int q  = q0 + ql;
            const float4 prA = *(const float4*)&pq[ql][0];
            const float4 prB = *(const float4*)&pq[ql][4];
            const float4 prC = *(const float4*)&pq[ql][8];
            const float4 prD = *(const float4*)&pq[ql][12];
            const float p0 = prA.x, p1 = prA.y, p2 = prA.z, p3 = prA.w;
            const float p4 = prB.x, p5v = prB.y, p6 = prB.z, p7 = prB.w;
            const float pxc = prC.x, pyc = prC.y;
            const float pax0 = prC.z, pay0 = prC.w, pax1 = prD.x, pay1 = prD.y;
            const float parea = prD.z;

            const float l1 = fabsf(p0 - g0) + fabsf(p1 - g1) + fabsf(p2 - g2)
                           + fabsf(p3 - g3) + fabsf(p4 - g4) + fabsf(p5v - g5)
                           + fabsf(p6 - g6) + fabsf(p7 - g7);

            const float ltx = fmaxf(pax0, gax0), lty = fmaxf(pay0, gay0);
            const float rbx = fminf(pax1, gax1), rby = fminf(pay1, gay1);
            const float iw = fmaxf(rbx - ltx, 0.f), ih = fmaxf(rby - lty, 0.f);
            const float inter = iw * ih;
            const float iou = inter / (parea + garea - inter + 1e-8f);

            const float ew = fmaxf(pax1, gax1) - fminf(pax0, gax0);
            const float eh = fmaxf(pay1, gay1) - fminf(pay0, gay0);
            const float cc2 = ew * ew + eh * eh + 1e-8f;
            const float dx = pxc - gxc, dy = pyc - gyc;
            const float diou = iou - (dx * dx + dy * dy) / cc2;

            const float cclass = lbuf[(2 * jj + qh) * 80 + lab];
            const float cost = 5.f * l1 + 2.f * cclass + 2.f * diou
                             + (fgf[ql] ? 0.f : 10000.f);

            const size_t o = ((size_t)b * Q_ + q) * G_ + g;
            out_cost[o] = cost;
            out_iou[o]  = iou;
            costT[((size_t)b * G_ + g) * Q_ + q] = cost;

            if (iou > t4) {
                if (iou > t0)      { t4 = t3; t3 = t2; t2 = t1; t1 = t0; t0 = iou; }
                else if (iou > t1) { t4 = t3; t3 = t2; t2 = t1; t1 = iou; }
                else if (iou > t2) { t4 = t3; t3 = t2; t2 = iou; }
                else if (iou > t3) { t4 = t3; t3 = iou; }
                else               { t4 = iou; }
            }
        }
    }

    // ---- write iou partials: [B*G][NCH][2][5] ----
    const size_t pbase = (((size_t)b * G_ + g) * NCH + ci) * 10 + qh * 5;
    piou[pbase + 0] = t0; piou[pbase + 1] = t1; piou[pbase + 2] = t2;
    piou[pbase + 3] = t3; piou[pbase + 4] = t4;
}

// ---------------------------------------------------------------------------
// Kernel E: row argmin of cost (first-index tie-break).  One wave per row.
// ---------------------------------------------------------------------------
__global__ __launch_bounds__(256) void ramin_kernel(
    const float* __restrict__ cost, int* __restrict__ ramin)
{
    const int wv = threadIdx.x >> 6, ln = threadIdx.x & 63;
    const int row = blockIdx.x * 4 + wv;  // row in [0, B*Q)
    const float2 c2v = ((const float2*)(cost + (size_t)row * G_))[ln];
    float v; int gg;
    if (c2v.x <= c2v.y) { v = c2v.x; gg = 2 * ln; }
    else                { v = c2v.y; gg = 2 * ln + 1; }
    for (int off = 32; off > 0; off >>= 1) {
        const float ov = __shfl_xor(v, off);
        const int   og = __shfl_xor(gg, off);
        if (ov < v || (ov == v && og < gg)) { v = ov; gg = og; }
    }
    if (ln == 0) ramin[row] = gg;
}

// ---------------------------------------------------------------------------
// Kernel B: per-column (block=256): exact bottom-5 of costT column (-> cand),
// top-5 iou from partials -> dyn_k, scatter (cnt, gsel).
// ---------------------------------------------------------------------------
__global__ __launch_bounds__(256) void dynk_scatter_kernel(
    const float* __restrict__ costT,
    const float* __restrict__ piou,
    u64* __restrict__ cand,
    int* __restrict__ cnt,
    int* __restrict__ gsel)
{
    const int col = blockIdx.x;          // b*G + g
    const int b = col >> 7, g = col & 127;
    const int tid = threadIdx.x;
    const int wv = tid >> 6, ln = tid & 63;

    __shared__ u64 wl[4][5];

    // ---- phase 1: per-thread bottom-5 over 16 column elements ----
    const float4* colp = (const float4*)(costT + (size_t)col * Q_);
    u64 k0 = U64MAX, k1 = U64MAX, k2 = U64MAX, k3 = U64MAX, k4 = U64MAX;
    #pragma unroll
    for (int s = 0; s < 4; ++s) {
        const int idx = tid + s * 256;
        const float4 c4 = colp[idx];
        const int qb = idx * 4;
        const float vv[4] = {c4.x, c4.y, c4.z, c4.w};
        #pragma unroll
        for (int j = 0; j < 4; ++j) {
            const u64 kk = packkey(vv[j], qb + j);
            if (kk < k4) {
                if (kk < k0)      { k4 = k3; k3 = k2; k2 = k1; k1 = k0; k0 = kk; }
                else if (kk < k1) { k4 = k3; k3 = k2; k2 = k1; k1 = kk; }
                else if (kk < k2) { k4 = k3; k3 = k2; k2 = kk; }
                else if (kk < k3) { k4 = k3; k3 = kk; }
                else              { k4 = kk; }
            }
        }
    }
    #pragma unroll
    for (int off = 1; off < 64; off <<= 1) {
        merge5_asc(k0, k1, k2, k3, k4,
                   __shfl_xor(k0, off), __shfl_xor(k1, off), __shfl_xor(k2, off),
                   __shfl_xor(k3, off), __shfl_xor(k4, off));
    }
    if (ln == 0) { wl[wv][0] = k0; wl[wv][1] = k1; wl[wv][2] = k2; wl[wv][3] = k3; wl[wv][4] = k4; }
    __syncthreads();

    // ---- phase 2 (wave 0): top-5 iou merge from 128 partial lists ----
    float t0 = -1e38f, t1 = -1e38f, t2 = -1e38f, t3 = -1e38f, t4 = -1e38f;
    if (tid < 64) {
        const size_t base = (size_t)col * (NCH * 10) + (size_t)tid * 10;
        t0 = piou[base + 0]; t1 = piou[base + 1]; t2 = piou[base + 2];
        t3 = piou[base + 3]; t4 = piou[base + 4];
        merge5_desc(t0, t1, t2, t3, t4,
                    piou[base + 5], piou[base + 6], piou[base + 7],
                    piou[base + 8], piou[base + 9]);
        #pragma unroll
        for (int off = 1; off < 64; off <<= 1) {
            merge5_desc(t0, t1, t2, t3, t4,
                        __shfl_xor(t0, off), __shfl_xor(t1, off), __shfl_xor(t2, off),
                        __shfl_xor(t3, off), __shfl_xor(t4, off));
        }
    }

    if (tid == 0) {
        u64 f0 = wl[0][0], f1 = wl[0][1], f2 = wl[0][2], f3 = wl[0][3], f4 = wl[0][4];
        merge5_asc(f0, f1, f2, f3, f4, wl[1][0], wl[1][1], wl[1][2], wl[1][3], wl[1][4]);
        merge5_asc(f0, f1, f2, f3, f4, wl[2][0], wl[2][1], wl[2][2], wl[2][3], wl[2][4]);
        merge5_asc(f0, f1, f2, f3, f4, wl[3][0], wl[3][1], wl[3][2], wl[3][3], wl[3][4]);
        cand[(size_t)col * 5 + 0] = f0;
        cand[(size_t)col * 5 + 1] = f1;
        cand[(size_t)col * 5 + 2] = f2;
        cand[(size_t)col * 5 + 3] = f3;
        cand[(size_t)col * 5 + 4] = f4;

        const float s = t0 + t1 + t2 + t3 + t4;
        int dynk = (int)s;
        if (dynk < 1) dynk = 1;
        if (dynk > 5) dynk = 5;
        const u64 ks[5] = {f0, f1, f2, f3, f4};
        #pragma unroll
        for (int i = 0; i < 5; ++i) {
            if (i < dynk) {
                const int q = (int)(ks[i] & 0xffffffffu);
                atomicAdd(&cnt[b * Q_ + q], 1);
                gsel[b * Q_ + q] = g;   // only read when cnt==1
            }
        }
    }
}

// ---------------------------------------------------------------------------
// Kernel C: per-batch event-driven refinement loop.
// Facts used (proven from penalty magnitudes): per-column argmin always lands
// on an unmatched row; rows never get re-assigned; columns never lose matches.
// Candidates = exact bottom-5 per column; fallback = full column scan.
// ---------------------------------------------------------------------------
__global__ __launch_bounds__(256) void loop_kernel(
    const float* __restrict__ costT,
    const int* __restrict__ cnt,
    const int* __restrict__ gsel,
    const int* __restrict__ ramin,
    const u64* __restrict__ cand,
    int* __restrict__ rmatch_final)
{
    const int b = blockIdx.x, tid = threadIdx.x;

    __shared__ short rmatch[Q_];            // 8 KB
    __shared__ unsigned char s_ra[Q_];      // 4 KB
    __shared__ int newh[Q_];                // 16 KB (zeroed once; re-zeroed per touch)
    __shared__ unsigned char newg[Q_];      // 4 KB
    __shared__ u64 scand[G_][5];            // 5 KB
    __shared__ int ptrs[G_], col_cnt[G_], unm_list[G_], prop[G_], fb_slot[G_], touched[G_];
    __shared__ int n_unm, n_fb, n_touch;
    __shared__ u64 red[4];

    for (int q = tid; q < Q_; q += 256) {
        const int c  = cnt[b * Q_ + q];
        const int ra = ramin[b * Q_ + q];
        s_ra[q] = (unsigned char)ra;
        newh[q] = 0;
        rmatch[q] = (c == 0) ? (short)-1
                             : (c == 1 ? (short)gsel[b * Q_ + q] : (short)ra);
    }
    if (tid < G_) { col_cnt[tid] = 0; ptrs[tid] = 0; }
    for (int i = tid; i < G_ * 5; i += 256)
        scand[i / 5][i % 5] = cand[(size_t)b * G_ * 5 + i];
    __syncthreads();
    for (int q = tid; q < Q_; q += 256)
        if (rmatch[q] >= 0) atomicAdd(&col_cnt[rmatch[q]], 1);
    __syncthreads();

    for (int it = 0; it < G_; ++it) {
        if (tid == 0) { n_unm = 0; n_fb = 0; n_touch = 0; }
        __syncthreads();
        if (tid < G_ && col_cnt[tid] == 0)
            unm_list[atomicAdd(&n_unm, 1)] = tid;
        __syncthreads();
        const int nu = n_unm;
        if (nu == 0) break;

        // propose: first unmatched candidate, else mark for fallback scan
        if (tid < nu) {
            const int g = unm_list[tid];
            int p = ptrs[g];
            int q = -1;
            while (p < 5) {
                const int cq = (int)(scand[g][p] & 0xffffffffu);
                if (rmatch[cq] < 0) { q = cq; break; }
                ++p;
            }
            ptrs[g] = p;
            prop[tid] = q;
            if (q < 0) fb_slot[atomicAdd(&n_fb, 1)] = tid;
        }
        __syncthreads();

        // fallback: whole-block lex-min over unmatched rows of the column
        const int nf = n_fb;
        for (int i = 0; i < nf; ++i) {
            const int slot = fb_slot[i];
            const int g = unm_list[slot];
            const float4* colp = (const float4*)(costT + ((size_t)b * G_ + g) * Q_);
            u64 best = U64MAX;
            #pragma unroll
            for (int s = 0; s < 4; ++s) {
                const int idx = tid + s * 256;
                const float4 c4 = colp[idx];
                const int qb = idx * 4;
                if (rmatch[qb]     < 0) best = umin64(best, packkey(c4.x, qb));
                if (rmatch[qb + 1] < 0) best = umin64(best, packkey(c4.y, qb + 1));
                if (rmatch[qb + 2] < 0) best = umin64(best, packkey(c4.z, qb + 2));
                if (rmatch[qb + 3] < 0) best = umin64(best, packkey(c4.w, qb + 3));
            }
            #pragma unroll
            for (int off = 1; off < 64; off <<= 1)
                best = umin64(best, __shfl_xor(best, off));
            if ((tid & 63) == 0) red[tid >> 6] = best;
            __syncthreads();
            if (tid == 0) {
                const u64 m = umin64(umin64(red[0], red[1]), umin64(red[2], red[3]));
                prop[slot] = (int)(m & 0xffffffffu);
            }
            __syncthreads();
        }

        // hits
        if (tid < nu) {
            const int q = prop[tid];
            newg[q] = (unsigned char)unm_list[tid];  // consumed only when nh==1
            if (atomicAdd(&newh[q], 1) == 0)
                touched[atomicAdd(&n_touch, 1)] = q;
        }
        __syncthreads();

        // resolve (dedup): hits only land on unmatched rows
        const int nt = n_touch;
        if (tid < nt) {
            const int q = touched[tid];
            const int nh = newh[q];
            const int gg = (nh == 1) ? (int)newg[q] : (int)s_ra[q];
            rmatch[q] = (short)gg;
            atomicAdd(&col_cnt[gg], 1);
            newh[q] = 0;
        }
        __syncthreads();
    }

    for (int q = tid; q < Q_; q += 256)
        rmatch_final[b * Q_ + q] = rmatch[q];
}

// ---------------------------------------------------------------------------
// Kernel D: expand rmatch -> full match plane (fully parallel float4 writes).
// ---------------------------------------------------------------------------
__global__ __launch_bounds__(256) void expand_kernel(
    const int* __restrict__ rmatch_final, float* __restrict__ out_match)
{
    const int idx = blockIdx.x * 256 + threadIdx.x;  // float4 index
    const int row = idx >> 5;                        // G/4 = 32 float4 per row
    const int gb  = (idx & 31) << 2;
    const int rm  = rmatch_final[row];
    float4 o;
    o.x = (rm == gb)     ? 1.f : 0.f;
    o.y = (rm == gb + 1) ? 1.f : 0.f;
    o.z = (rm == gb + 2) ? 1.f : 0.f;
    o.w = (rm == gb + 3) ? 1.f : 0.f;
    ((float4*)out_match)[idx] = o;
}

extern "C" void kernel_launch(void* const* d_in, const int* in_sizes, int n_in,
                              void* d_out, int out_size, void* d_ws, size_t ws_size,
                              hipStream_t stream) {
    const float* logits  = (const float*)d_in[0];
    const float* pboxes  = (const float*)d_in[1];
    const float* gboxes  = (const float*)d_in[2];
    const int*   glabels = (const int*)d_in[3];

    float* out = (float*)d_out;
    const size_t BQG = (size_t)B_ * Q_ * G_;
    float* out_match = out;
    float* out_cost  = out + BQG;
    float* out_iou   = out + 2 * BQG;

    // workspace layout (~61 MB)
    char* ws = (char*)d_ws;
    size_t off = 0;
    float* costT  = (float*)(ws + off); off += (size_t)B_ * G_ * Q_ * 4;
    float* posneg = (float*)(ws + off); off += (size_t)B_ * Q_ * C_ * 4;
    float* piou   = (float*)(ws + off); off += (size_t)B_ * G_ * NCH * 10 * 4;
    u64*   cand   = (u64*)  (ws + off); off += (size_t)B_ * G_ * 5 * 8;
    int*   ramin  = (int*)  (ws + off); off += (size_t)B_ * Q_ * 4;
    int*   cnt    = (int*)  (ws + off); off += (size_t)B_ * Q_ * 4;
    int*   gsel   = (int*)  (ws + off); off += (size_t)B_ * Q_ * 4;
    int*   rmf    = (int*)  (ws + off); off += (size_t)B_ * Q_ * 4;

    hipMemsetAsync(cnt, 0, (size_t)B_ * Q_ * 4, stream);
    posneg_kernel<<<B_ * Q_ * C_ / 256, 256, 0, stream>>>(logits, posneg);
    fused_cost_kernel<<<dim3(NCH, B_), 256, 0, stream>>>(
        posneg, pboxes, gboxes, glabels, out_cost, out_iou, costT, piou);
    ramin_kernel<<<B_ * Q_ / 4, 256, 0, stream>>>(out_cost, ramin);
    dynk_scatter_kernel<<<B_ * G_, 256, 0, stream>>>(costT, piou, cand, cnt, gsel);
    loop_kernel<<<B_, 256, 0, stream>>>(costT, cnt, gsel, ramin, cand, rmf);
    expand_kernel<<<(int)(BQG / 4 / 256), 256, 0, stream>>>(rmf, out_match);
}

// Round 5
// 214.917 us; speedup vs baseline: 2.8099x; 1.1144x over previous
//
#include <hip/hip_runtime.h>
#include <cstdint>
#include <cstddef>

#define B_ 16
#define Q_ 4096
#define G_ 128
#define C_ 80
#define QCHUNK 32
#define NCH (Q_ / QCHUNK)   // 128 chunks

typedef unsigned long long u64;
#define U64MAX 0xffffffffffffffffull

// pack (cost,q) into a sortable u64 key: asc key order == lex (cost asc, q asc)
__device__ __forceinline__ u64 packkey(float v, int q) {
    unsigned int bts = __float_as_uint(v);
    if (bts == 0x80000000u) bts = 0u;  // -0.0 -> +0.0
    bts = (bts & 0x80000000u) ? ~bts : (bts | 0x80000000u);
    return ((u64)bts << 32) | (unsigned int)q;
}

__device__ __forceinline__ u64 umin64(u64 a, u64 b) { return a < b ? a : b; }
__device__ __forceinline__ u64 umax64(u64 a, u64 b) { return a > b ? a : b; }

// merge two desc-sorted 5-lists -> top-5 desc (branchless network)
__device__ __forceinline__ void merge5_desc(
    float& a0, float& a1, float& a2, float& a3, float& a4,
    float b0, float b1, float b2, float b3, float b4)
{
    const float r0 = fmaxf(a0, b0);
    const float r1 = fmaxf(fmaxf(a1, b1), fminf(a0, b0));
    const float r2 = fmaxf(fmaxf(a2, b2), fmaxf(fminf(a0, b1), fminf(a1, b0)));
    const float r3 = fmaxf(fmaxf(a3, b3),
                     fmaxf(fminf(a0, b2), fmaxf(fminf(a1, b1), fminf(a2, b0))));
    const float r4 = fmaxf(fmaxf(a4, b4),
                     fmaxf(fmaxf(fminf(a0, b3), fminf(a3, b0)),
                           fmaxf(fminf(a1, b2), fminf(a2, b1))));
    a0 = r0; a1 = r1; a2 = r2; a3 = r3; a4 = r4;
}

// merge two asc-sorted 5-lists of u64 keys -> bottom-5 asc
__device__ __forceinline__ void merge5_asc(
    u64& a0, u64& a1, u64& a2, u64& a3, u64& a4,
    u64 b0, u64 b1, u64 b2, u64 b3, u64 b4)
{
    const u64 r0 = umin64(a0, b0);
    const u64 r1 = umin64(umin64(a1, b1), umax64(a0, b0));
    const u64 r2 = umin64(umin64(a2, b2), umin64(umax64(a0, b1), umax64(a1, b0)));
    const u64 r3 = umin64(umin64(a3, b3),
                   umin64(umax64(a0, b2), umin64(umax64(a1, b1), umax64(a2, b0))));
    const u64 r4 = umin64(umin64(a4, b4),
                   umin64(umin64(umax64(a0, b3), umax64(a3, b0)),
                          umin64(umax64(a1, b2), umax64(a2, b1))));
    a0 = r0; a1 = r1; a2 = r2; a3 = r3; a4 = r4;
}

// ---------------------------------------------------------------------------
// Kernel P: focal class cost table posneg[B][Q][C] (elementwise, coalesced).
// ---------------------------------------------------------------------------
__global__ __launch_bounds__(256) void posneg_kernel(
    const float* __restrict__ logits, float* __restrict__ posneg)
{
    const int i = blockIdx.x * 256 + threadIdx.x;
    const float x = logits[i];
    float p;
    if (x >= 0.f) { const float e = expf(-x); p = 1.f / (1.f + e); }
    else          { const float e = expf(x);  p = e / (1.f + e); }
    const float pos = 0.25f * (1.f - p) * (1.f - p) * (-logf(p + 1e-8f));
    const float neg = 0.75f * p * p * (-logf(1.f - p + 1e-8f));
    posneg[i] = pos - neg;
}

// ---------------------------------------------------------------------------
// Kernel A: fused cost/iou + per-chunk top-5 iou partial (halves merged).
// Block = (chunk of 32 q's, batch). Thread: g = tid&127, qh = tid>>7.
// costT written via LDS tile -> coalesced (no 64-way scatter).
// ---------------------------------------------------------------------------
__global__ __launch_bounds__(256) void fused_cost_kernel(
    const float* __restrict__ posneg,
    const float* __restrict__ pboxes,
    const float* __restrict__ gboxes,
    const int*   __restrict__ glabels,
    float* __restrict__ out_cost,
    float* __restrict__ out_iou,
    float* __restrict__ costT,
    float* __restrict__ piou)
{
    const int tid = threadIdx.x;
    const int g   = tid & 127;
    const int qh  = tid >> 7;
    const int ci  = blockIdx.x, b = blockIdx.y;
    const int q0  = ci * QCHUNK;

    __shared__ float pq[QCHUNK][16];
    __shared__ int   fgf[QCHUNK];
    __shared__ float lbuf[16 * 80];
    __shared__ float ctile[QCHUNK][G_ + 1];   // +1 pad: costT readout stride
    __shared__ float phalf[G_][5];

    // ---- per-thread gt constants ----
    const float4* gb4 = (const float4*)(gboxes + ((size_t)b * G_ + g) * 8);
    const float4 gA = gb4[0], gB = gb4[1];
    const float g0 = gA.x, g1 = gA.y, g2 = gA.z, g3 = gA.w;
    const float g4 = gB.x, g5 = gB.y, g6 = gB.z, g7 = gB.w;
    const float gxc = (g0 + g2 + g4 + g6) * 0.25f;
    const float gyc = (g1 + g3 + g5 + g7) * 0.25f;
    const float gw = sqrtf((g0 - g2) * (g0 - g2) + (g1 - g3) * (g1 - g3));
    const float gh = sqrtf((g2 - g4) * (g2 - g4) + (g3 - g5) * (g3 - g5));
    const float gax0 = gxc - gw * 0.5f, gay0 = gyc - gh * 0.5f;
    const float gax1 = gxc + gw * 0.5f, gay1 = gyc + gh * 0.5f;
    const float garea = (gax1 - gax0) * (gay1 - gay0);
    const float v1x = g2 - g0, v1y = g3 - g1, v2x = g4 - g0, v2y = g5 - g1;
    const float gt_area = fabsf(v1x * v2y - v1y * v2x) * 0.5f;
    const float mxx = fmaxf(fmaxf(g0, g2), fmaxf(g4, g6));
    const float mnx = fminf(fminf(g0, g2), fminf(g4, g6));
    const float mxy = fmaxf(fmaxf(g1, g3), fmaxf(g5, g7));
    const float mny = fminf(fminf(g1, g3), fminf(g5, g7));
    const float dgx = mxx - mnx, dgy = mxy - mny;
    const float radius = sqrtf(dgx * dgx + dgy * dgy) / 32.0f;
    const float thresh = gt_area / radius;
    const int lab = glabels[b * G_ + g];

    // ---- stage pred boxes (32 q x 8 floats = 64 float4) ----
    if (tid < 64) {
        const float4 v = ((const float4*)(pboxes + ((size_t)b * Q_ + q0) * 8))[tid];
        *(float4*)&pq[tid >> 1][(tid & 1) * 4] = v;
    }
    __syncthreads();
    if (tid < QCHUNK) {
        const float* pr = pq[tid];
        const float p0 = pr[0], p1 = pr[1], p2 = pr[2], p3 = pr[3];
        const float p4 = pr[4], p5v = pr[5], p6 = pr[6], p7 = pr[7];
        const float pxc = (p0 + p2 + p4 + p6) * 0.25f;
        const float pyc = (p1 + p3 + p5v + p7) * 0.25f;
        const float pw = sqrtf((p0 - p2) * (p0 - p2) + (p1 - p3) * (p1 - p3));
        const float ph = sqrtf((p2 - p4) * (p2 - p4) + (p3 - p5v) * (p3 - p5v));
        pq[tid][8]  = pxc;
        pq[tid][9]  = pyc;
        pq[tid][10] = pxc - pw * 0.5f;
        pq[tid][11] = pyc - ph * 0.5f;
        pq[tid][12] = pxc + pw * 0.5f;
        pq[tid][13] = pyc + ph * 0.5f;
        pq[tid][14] = pw * ph;
        fgf[tid] = 0;
    }
    __syncthreads();

    // ---- pass 1: fg mask (any over g) ----
    const int lane0 = ((tid & 63) == 0);
    for (int i = 0; i < QCHUNK / 2; ++i) {
        const int ql = 2 * i + qh;
        const float dx = pq[ql][8] - gxc, dy = pq[ql][9] - gyc;
        const int in = sqrtf(dx * dx + dy * dy) <= thresh;
        const int anyin = __any(in);
        if (anyin && lane0) fgf[ql] = 1;
    }

    // ---- pass 2: full cost + running top-5 iou ----
    float t0 = -1e38f, t1 = -1e38f, t2 = -1e38f, t3 = -1e38f, t4 = -1e38f;

    for (int sc = 0; sc < QCHUNK / 16; ++sc) {
        __syncthreads();  // also covers fgf hazard on sc==0
        for (int j = tid; j < 16 * 80; j += 256)
            lbuf[j] = posneg[((size_t)b * Q_ + q0 + sc * 16) * 80 + j];
        __syncthreads();
        #pragma unroll
        for (int jj = 0; jj < 8; ++jj) {
            const int ql = sc * 16 + 2 * jj + qh;
            const int q  = q0 + ql;
            const float4 prA = *(const float4*)&pq[ql][0];
            const float4 prB = *(const float4*)&pq[ql][4];
            const float4 prC = *(const float4*)&pq[ql][8];
            const float4 prD = *(const float4*)&pq[ql][12];
            const float p0 = prA.x, p1 = prA.y, p2 = prA.z, p3 = prA.w;
            const float p4 = prB.x, p5v = prB.y, p6 = prB.z, p7 = prB.w;
            const float pxc = prC.x, pyc = prC.y;
            const float pax0 = prC.z, pay0 = prC.w, pax1 = prD.x, pay1 = prD.y;
            const float parea = prD.z;

            const float l1 = fabsf(p0 - g0) + fabsf(p1 - g1) + fabsf(p2 - g2)
                           + fabsf(p3 - g3) + fabsf(p4 - g4) + fabsf(p5v - g5)
                           + fabsf(p6 - g6) + fabsf(p7 - g7);

            const float ltx = fmaxf(pax0, gax0), lty = fmaxf(pay0, gay0);
            const float rbx = fminf(pax1, gax1), rby = fminf(pay1, gay1);
            const float iw = fmaxf(rbx - ltx, 0.f), ih = fmaxf(rby - lty, 0.f);
            const float inter = iw * ih;
            const float iou = inter / (parea + garea - inter + 1e-8f);

            const float ew = fmaxf(pax1, gax1) - fminf(pax0, gax0);
            const float eh = fmaxf(pay1, gay1) - fminf(pay0, gay0);
            const float cc2 = ew * ew + eh * eh + 1e-8f;
            const float dx = pxc - gxc, dy = pyc - gyc;
            const float diou = iou - (dx * dx + dy * dy) / cc2;

            const float cclass = lbuf[(2 * jj + qh) * 80 + lab];
            const float cost = 5.f * l1 + 2.f * cclass + 2.f * diou
                             + (fgf[ql] ? 0.f : 10000.f);

            const size_t o = ((size_t)b * Q_ + q) * G_ + g;
            out_cost[o] = cost;
            out_iou[o]  = iou;
            ctile[ql][g] = cost;

            if (iou > t4) {
                if (iou > t0)      { t4 = t3; t3 = t2; t2 = t1; t1 = t0; t0 = iou; }
                else if (iou > t1) { t4 = t3; t3 = t2; t2 = t1; t1 = iou; }
                else if (iou > t2) { t4 = t3; t3 = t2; t2 = iou; }
                else if (iou > t3) { t4 = t3; t3 = iou; }
                else               { t4 = iou; }
            }
        }
    }

    // ---- merge q-halves of top-5, write single list per (col, chunk) ----
    if (qh == 1) {
        phalf[g][0] = t0; phalf[g][1] = t1; phalf[g][2] = t2;
        phalf[g][3] = t3; phalf[g][4] = t4;
    }
    __syncthreads();   // also protects ctile completion for readout below
    if (qh == 0) {
        merge5_desc(t0, t1, t2, t3, t4,
                    phalf[g][0], phalf[g][1], phalf[g][2], phalf[g][3], phalf[g][4]);
        const size_t pbase = (((size_t)b * G_ + g) * NCH + ci) * 5;
        piou[pbase + 0] = t0; piou[pbase + 1] = t1; piou[pbase + 2] = t2;
        piou[pbase + 3] = t3; piou[pbase + 4] = t4;
    }

    // ---- coalesced costT writeout from LDS tile ----
    for (int t = tid; t < QCHUNK * G_ / 4; t += 256) {
        const int gg = t >> 3;          // 8 float4 per g-row (QCHUNK/4)
        const int k  = (t & 7) << 2;
        float4 o;
        o.x = ctile[k + 0][gg]; o.y = ctile[k + 1][gg];
        o.z = ctile[k + 2][gg]; o.w = ctile[k + 3][gg];
        *(float4*)&costT[((size_t)b * G_ + gg) * Q_ + q0 + k] = o;
    }
}

// ---------------------------------------------------------------------------
// Kernel E: row argmin of cost (first-index tie-break).  One wave per row.
// ---------------------------------------------------------------------------
__global__ __launch_bounds__(256) void ramin_kernel(
    const float* __restrict__ cost, int* __restrict__ ramin)
{
    const int wv = threadIdx.x >> 6, ln = threadIdx.x & 63;
    const int row = blockIdx.x * 4 + wv;  // row in [0, B*Q)
    const float2 c2v = ((const float2*)(cost + (size_t)row * G_))[ln];
    float v; int gg;
    if (c2v.x <= c2v.y) { v = c2v.x; gg = 2 * ln; }
    else                { v = c2v.y; gg = 2 * ln + 1; }
    for (int off = 32; off > 0; off >>= 1) {
        const float ov = __shfl_xor(v, off);
        const int   og = __shfl_xor(gg, off);
        if (ov < v || (ov == v && og < gg)) { v = ov; gg = og; }
    }
    if (ln == 0) ramin[row] = gg;
}

// ---------------------------------------------------------------------------
// Kernel B: per-column (block=256): exact bottom-5 of costT column (-> cand),
// top-5 iou from partials -> dyn_k, scatter (cnt, gsel).
// ---------------------------------------------------------------------------
__global__ __launch_bounds__(256) void dynk_scatter_kernel(
    const float* __restrict__ costT,
    const float* __restrict__ piou,
    u64* __restrict__ cand,
    int* __restrict__ cnt,
    int* __restrict__ gsel)
{
    const int col = blockIdx.x;          // b*G + g
    const int b = col >> 7, g = col & 127;
    const int tid = threadIdx.x;
    const int wv = tid >> 6, ln = tid & 63;

    __shared__ u64 wl[4][5];

    // ---- phase 1: per-thread bottom-5 over 16 column elements ----
    const float4* colp = (const float4*)(costT + (size_t)col * Q_);
    u64 k0 = U64MAX, k1 = U64MAX, k2 = U64MAX, k3 = U64MAX, k4 = U64MAX;
    #pragma unroll
    for (int s = 0; s < 4; ++s) {
        const int idx = tid + s * 256;
        const float4 c4 = colp[idx];
        const int qb = idx * 4;
        const float vv[4] = {c4.x, c4.y, c4.z, c4.w};
        #pragma unroll
        for (int j = 0; j < 4; ++j) {
            const u64 kk = packkey(vv[j], qb + j);
            if (kk < k4) {
                if (kk < k0)      { k4 = k3; k3 = k2; k2 = k1; k1 = k0; k0 = kk; }
                else if (kk < k1) { k4 = k3; k3 = k2; k2 = k1; k1 = kk; }
                else if (kk < k2) { k4 = k3; k3 = k2; k2 = kk; }
                else if (kk < k3) { k4 = k3; k3 = kk; }
                else              { k4 = kk; }
            }
        }
    }
    #pragma unroll
    for (int off = 1; off < 64; off <<= 1) {
        merge5_asc(k0, k1, k2, k3, k4,
                   __shfl_xor(k0, off), __shfl_xor(k1, off), __shfl_xor(k2, off),
                   __shfl_xor(k3, off), __shfl_xor(k4, off));
    }
    if (ln == 0) { wl[wv][0] = k0; wl[wv][1] = k1; wl[wv][2] = k2; wl[wv][3] = k3; wl[wv][4] = k4; }
    __syncthreads();

    // ---- phase 2 (wave 0): top-5 iou merge from 128 chunk lists ----
    float t0 = -1e38f, t1 = -1e38f, t2 = -1e38f, t3 = -1e38f, t4 = -1e38f;
    if (tid < 64) {
        const size_t base = (size_t)col * (NCH * 5) + (size_t)tid * 10;
        t0 = piou[base + 0]; t1 = piou[base + 1]; t2 = piou[base + 2];
        t3 = piou[base + 3]; t4 = piou[base + 4];
        merge5_desc(t0, t1, t2, t3, t4,
                    piou[base + 5], piou[base + 6], piou[base + 7],
                    piou[base + 8], piou[base + 9]);
        #pragma unroll
        for (int off = 1; off < 64; off <<= 1) {
            merge5_desc(t0, t1, t2, t3, t4,
                        __shfl_xor(t0, off), __shfl_xor(t1, off), __shfl_xor(t2, off),
                        __shfl_xor(t3, off), __shfl_xor(t4, off));
        }
    }

    if (tid == 0) {
        u64 f0 = wl[0][0], f1 = wl[0][1], f2 = wl[0][2], f3 = wl[0][3], f4 = wl[0][4];
        merge5_asc(f0, f1, f2, f3, f4, wl[1][0], wl[1][1], wl[1][2], wl[1][3], wl[1][4]);
        merge5_asc(f0, f1, f2, f3, f4, wl[2][0], wl[2][1], wl[2][2], wl[2][3], wl[2][4]);
        merge5_asc(f0, f1, f2, f3, f4, wl[3][0], wl[3][1], wl[3][2], wl[3][3], wl[3][4]);
        cand[(size_t)col * 5 + 0] = f0;
        cand[(size_t)col * 5 + 1] = f1;
        cand[(size_t)col * 5 + 2] = f2;
        cand[(size_t)col * 5 + 3] = f3;
        cand[(size_t)col * 5 + 4] = f4;

        const float s = t0 + t1 + t2 + t3 + t4;
        int dynk = (int)s;
        if (dynk < 1) dynk = 1;
        if (dynk > 5) dynk = 5;
        const u64 ks[5] = {f0, f1, f2, f3, f4};
        #pragma unroll
        for (int i = 0; i < 5; ++i) {
            if (i < dynk) {
                const int q = (int)(ks[i] & 0xffffffffu);
                atomicAdd(&cnt[b * Q_ + q], 1);
                gsel[b * Q_ + q] = g;   // only read when cnt==1
            }
        }
    }
}

// ---------------------------------------------------------------------------
// Kernel C: per-batch event-driven refinement loop.
// Hits only land on unmatched rows (matched rows carry >=100000 penalty while
// unmatched row costs < 40000); rows never re-assign; columns never unmatch.
// Wave-parallel fallback refills the column's candidate list with the bottom-5
// currently-unmatched rows (prefix-validity: any smaller unmatched row at a
// later time would already have been in this list and matched earlier).
// ---------------------------------------------------------------------------
__global__ __launch_bounds__(256) void loop_kernel(
    const float* __restrict__ costT,
    const int* __restrict__ cnt,
    const int* __restrict__ gsel,
    const int* __restrict__ ramin,
    const u64* __restrict__ cand,
    int* __restrict__ rmatch_final)
{
    const int b = blockIdx.x, tid = threadIdx.x;
    const int wv = tid >> 6, ln = tid & 63;

    __shared__ short rmatch[Q_];            // 8 KB
    __shared__ unsigned char s_ra[Q_];      // 4 KB
    __shared__ int newh[Q_];                // 16 KB
    __shared__ unsigned char newg[Q_];      // 4 KB
    __shared__ u64 scand[G_][5];            // 5 KB
    __shared__ int ptrs[G_], col_cnt[G_], unm_list[G_], prop[G_], fb_slot[G_], touched[G_];
    __shared__ int n_unm, n_fb, n_touch;

    for (int q = tid; q < Q_; q += 256) {
        const int c  = cnt[b * Q_ + q];
        const int ra = ramin[b * Q_ + q];
        s_ra[q] = (unsigned char)ra;
        newh[q] = 0;
        rmatch[q] = (c == 0) ? (short)-1
                             : (c == 1 ? (short)gsel[b * Q_ + q] : (short)ra);
    }
    if (tid < G_) { col_cnt[tid] = 0; ptrs[tid] = 0; }
    for (int i = tid; i < G_ * 5; i += 256)
        scand[i / 5][i % 5] = cand[(size_t)b * G_ * 5 + i];
    __syncthreads();
    for (int q = tid; q < Q_; q += 256)
        if (rmatch[q] >= 0) atomicAdd(&col_cnt[rmatch[q]], 1);
    __syncthreads();

    for (int it = 0; it < G_; ++it) {
        if (tid == 0) { n_unm = 0; n_fb = 0; n_touch = 0; }
        __syncthreads();
        if (tid < G_ && col_cnt[tid] == 0)
            unm_list[atomicAdd(&n_unm, 1)] = tid;
        __syncthreads();
        const int nu = n_unm;
        if (nu == 0) break;

        // propose: first unmatched candidate, else mark for fallback scan
        if (tid < nu) {
            const int g = unm_list[tid];
            int p = ptrs[g];
            int q = -1;
            while (p < 5) {
                const int cq = (int)(scand[g][p] & 0xffffffffu);
                if (rmatch[cq] < 0) { q = cq; break; }
                ++p;
            }
            ptrs[g] = p;
            prop[tid] = q;
            if (q < 0) fb_slot[atomicAdd(&n_fb, 1)] = tid;
        }
        __syncthreads();

        // wave-parallel fallback: bottom-5 unmatched of the column + refill
        const int nf = n_fb;
        for (int i = wv; i < nf; i += 4) {
            const int slot = fb_slot[i];
            const int g = unm_list[slot];
            const float4* colp = (const float4*)(costT + ((size_t)b * G_ + g) * Q_);
            u64 k0 = U64MAX, k1 = U64MAX, k2 = U64MAX, k3 = U64MAX, k4 = U64MAX;
            #pragma unroll 4
            for (int s = 0; s < Q_ / 256; ++s) {
                const int idx = ln + s * 64;
                const float4 c4 = colp[idx];
                const int qb = idx * 4;
                const float vv[4] = {c4.x, c4.y, c4.z, c4.w};
                #pragma unroll
                for (int j = 0; j < 4; ++j) {
                    if (rmatch[qb + j] < 0) {
                        const u64 kk = packkey(vv[j], qb + j);
                        if (kk < k4) {
                            if (kk < k0)      { k4 = k3; k3 = k2; k2 = k1; k1 = k0; k0 = kk; }
                            else if (kk < k1) { k4 = k3; k3 = k2; k2 = k1; k1 = kk; }
                            else if (kk < k2) { k4 = k3; k3 = k2; k2 = kk; }
                            else if (kk < k3) { k4 = k3; k3 = kk; }
                            else              { k4 = kk; }
                        }
                    }
                }
            }
            #pragma unroll
            for (int off = 1; off < 64; off <<= 1) {
                merge5_asc(k0, k1, k2, k3, k4,
                           __shfl_xor(k0, off), __shfl_xor(k1, off), __shfl_xor(k2, off),
                           __shfl_xor(k3, off), __shfl_xor(k4, off));
            }
            if (ln == 0) {
                scand[g][0] = k0; scand[g][1] = k1; scand[g][2] = k2;
                scand[g][3] = k3; scand[g][4] = k4;
                ptrs[g] = 0;
                prop[slot] = (int)(k0 & 0xffffffffu);
            }
        }
        __syncthreads();

        // hits
        if (tid < nu) {
            const int q = prop[tid];
            newg[q] = (unsigned char)unm_list[tid];  // consumed only when nh==1
            if (atomicAdd(&newh[q], 1) == 0)
                touched[atomicAdd(&n_touch, 1)] = q;
        }
        __syncthreads();

        // resolve (dedup): hits only land on unmatched rows
        const int nt = n_touch;
        if (tid < nt) {
            const int q = touched[tid];
            const int nh = newh[q];
            const int gg = (nh == 1) ? (int)newg[q] : (int)s_ra[q];
            rmatch[q] = (short)gg;
            atomicAdd(&col_cnt[gg], 1);
            newh[q] = 0;
        }
        __syncthreads();
    }

    for (int q = tid; q < Q_; q += 256)
        rmatch_final[b * Q_ + q] = rmatch[q];
}

// ---------------------------------------------------------------------------
// Kernel D: expand rmatch -> full match plane (fully parallel float4 writes).
// ---------------------------------------------------------------------------
__global__ __launch_bounds__(256) void expand_kernel(
    const int* __restrict__ rmatch_final, float* __restrict__ out_match)
{
    const int idx = blockIdx.x * 256 + threadIdx.x;  // float4 index
    const int row = idx >> 5;                        // G/4 = 32 float4 per row
    const int gb  = (idx & 31) << 2;
    const int rm  = rmatch_final[row];
    float4 o;
    o.x = (rm == gb)     ? 1.f : 0.f;
    o.y = (rm == gb + 1) ? 1.f : 0.f;
    o.z = (rm == gb + 2) ? 1.f : 0.f;
    o.w = (rm == gb + 3) ? 1.f : 0.f;
    ((float4*)out_match)[idx] = o;
}

extern "C" void kernel_launch(void* const* d_in, const int* in_sizes, int n_in,
                              void* d_out, int out_size, void* d_ws, size_t ws_size,
                              hipStream_t stream) {
    const float* logits  = (const float*)d_in[0];
    const float* pboxes  = (const float*)d_in[1];
    const float* gboxes  = (const float*)d_in[2];
    const int*   glabels = (const int*)d_in[3];

    float* out = (float*)d_out;
    const size_t BQG = (size_t)B_ * Q_ * G_;
    float* out_match = out;
    float* out_cost  = out + BQG;
    float* out_iou   = out + 2 * BQG;

    // workspace layout (~61 MB)
    char* ws = (char*)d_ws;
    size_t off = 0;
    float* costT  = (float*)(ws + off); off += (size_t)B_ * G_ * Q_ * 4;
    float* posneg = (float*)(ws + off); off += (size_t)B_ * Q_ * C_ * 4;
    float* piou   = (float*)(ws + off); off += (size_t)B_ * G_ * NCH * 5 * 4;
    u64*   cand   = (u64*)  (ws + off); off += (size_t)B_ * G_ * 5 * 8;
    int*   ramin  = (int*)  (ws + off); off += (size_t)B_ * Q_ * 4;
    int*   cnt    = (int*)  (ws + off); off += (size_t)B_ * Q_ * 4;
    int*   gsel   = (int*)  (ws + off); off += (size_t)B_ * Q_ * 4;
    int*   rmf    = (int*)  (ws + off); off += (size_t)B_ * Q_ * 4;

    hipMemsetAsync(cnt, 0, (size_t)B_ * Q_ * 4, stream);
    posneg_kernel<<<B_ * Q_ * C_ / 256, 256, 0, stream>>>(logits, posneg);
    fused_cost_kernel<<<dim3(NCH, B_), 256, 0, stream>>>(
        posneg, pboxes, gboxes, glabels, out_cost, out_iou, costT, piou);
    ramin_kernel<<<B_ * Q_ / 4, 256, 0, stream>>>(out_cost, ramin);
    dynk_scatter_kernel<<<B_ * G_, 256, 0, stream>>>(costT, piou, cand, cnt, gsel);
    loop_kernel<<<B_, 256, 0, stream>>>(costT, cnt, gsel, ramin, cand, rmf);
    expand_kernel<<<(int)(BQG / 4 / 256), 256, 0, stream>>>(rmf, out_match);
}

// Round 6
// 211.419 us; speedup vs baseline: 2.8564x; 1.0165x over previous
//
#include <hip/hip_runtime.h>
#include <cstdint>
#include <cstddef>

#define B_ 16
#define Q_ 4096
#define G_ 128
#define C_ 80
#define QCHUNK 32
#define NCH (Q_ / QCHUNK)   // 128 chunks

typedef unsigned long long u64;
#define U64MAX 0xffffffffffffffffull

__device__ __forceinline__ bool lexless(float v1, int q1, float v2, int q2) {
    return v1 < v2 || (v1 == v2 && q1 < q2);
}

// pack (cost,q) into a sortable u64 key: asc key order == lex (cost asc, q asc)
__device__ __forceinline__ u64 packkey(float v, int q) {
    unsigned int bts = __float_as_uint(v);
    if (bts == 0x80000000u) bts = 0u;  // -0.0 -> +0.0
    bts = (bts & 0x80000000u) ? ~bts : (bts | 0x80000000u);
    return ((u64)bts << 32) | (unsigned int)q;
}

__device__ __forceinline__ u64 umin64(u64 a, u64 b) { return a < b ? a : b; }
__device__ __forceinline__ u64 umax64(u64 a, u64 b) { return a > b ? a : b; }

// merge two desc-sorted 5-lists -> top-5 desc (branchless network)
__device__ __forceinline__ void merge5_desc(
    float& a0, float& a1, float& a2, float& a3, float& a4,
    float b0, float b1, float b2, float b3, float b4)
{
    const float r0 = fmaxf(a0, b0);
    const float r1 = fmaxf(fmaxf(a1, b1), fminf(a0, b0));
    const float r2 = fmaxf(fmaxf(a2, b2), fmaxf(fminf(a0, b1), fminf(a1, b0)));
    const float r3 = fmaxf(fmaxf(a3, b3),
                     fmaxf(fminf(a0, b2), fmaxf(fminf(a1, b1), fminf(a2, b0))));
    const float r4 = fmaxf(fmaxf(a4, b4),
                     fmaxf(fmaxf(fminf(a0, b3), fminf(a3, b0)),
                           fmaxf(fminf(a1, b2), fminf(a2, b1))));
    a0 = r0; a1 = r1; a2 = r2; a3 = r3; a4 = r4;
}

// merge two asc-sorted 5-lists of u64 keys -> bottom-5 asc
__device__ __forceinline__ void merge5_asc(
    u64& a0, u64& a1, u64& a2, u64& a3, u64& a4,
    u64 b0, u64 b1, u64 b2, u64 b3, u64 b4)
{
    const u64 r0 = umin64(a0, b0);
    const u64 r1 = umin64(umin64(a1, b1), umax64(a0, b0));
    const u64 r2 = umin64(umin64(a2, b2), umin64(umax64(a0, b1), umax64(a1, b0)));
    const u64 r3 = umin64(umin64(a3, b3),
                   umin64(umax64(a0, b2), umin64(umax64(a1, b1), umax64(a2, b0))));
    const u64 r4 = umin64(umin64(a4, b4),
                   umin64(umin64(umax64(a0, b3), umax64(a3, b0)),
                          umin64(umax64(a1, b2), umax64(a2, b1))));
    a0 = r0; a1 = r1; a2 = r2; a3 = r3; a4 = r4;
}

__device__ __forceinline__ float focal_cost(float x) {
    float p;
    if (x >= 0.f) { const float e = expf(-x); p = 1.f / (1.f + e); }
    else          { const float e = expf(x);  p = e / (1.f + e); }
    const float pos = 0.25f * (1.f - p) * (1.f - p) * (-logf(p + 1e-8f));
    const float neg = 0.75f * p * p * (-logf(1.f - p + 1e-8f));
    return pos - neg;
}

// ---------------------------------------------------------------------------
// Kernel A: fused cost/iou + focal (in-LDS) + per-chunk top-5 iou partial +
// in-kernel row-argmin (ramin) + coalesced costT via per-subchunk LDS tile.
// Block = (chunk of 32 q's, batch). Thread: g = tid&127, qh = tid>>7.
// LDS ~17.7 KB -> 8 blocks/CU (grid = 2048 = 8/CU exactly).
// ---------------------------------------------------------------------------
__global__ __launch_bounds__(256) void fused_cost_kernel(
    const float* __restrict__ logits,
    const float* __restrict__ pboxes,
    const float* __restrict__ gboxes,
    const int*   __restrict__ glabels,
    float* __restrict__ out_cost,
    float* __restrict__ out_iou,
    float* __restrict__ costT,
    float* __restrict__ piou,
    int*   __restrict__ ramin)
{
    const int tid = threadIdx.x;
    const int g   = tid & 127;
    const int qh  = tid >> 7;
    const int ci  = blockIdx.x, b = blockIdx.y;
    const int q0  = ci * QCHUNK;

    __shared__ float pq[QCHUNK][16];
    __shared__ int   fgf[QCHUNK];
    __shared__ float lbuf[16 * 80];        // focal table for current subchunk
    __shared__ float ctile[16][G_ + 1];    // cost tile for current subchunk
    __shared__ float phalf[G_][5];

    // ---- per-thread gt constants ----
    const float4* gb4 = (const float4*)(gboxes + ((size_t)b * G_ + g) * 8);
    const float4 gA = gb4[0], gB = gb4[1];
    const float g0 = gA.x, g1 = gA.y, g2 = gA.z, g3 = gA.w;
    const float g4 = gB.x, g5 = gB.y, g6 = gB.z, g7 = gB.w;
    const float gxc = (g0 + g2 + g4 + g6) * 0.25f;
    const float gyc = (g1 + g3 + g5 + g7) * 0.25f;
    const float gw = sqrtf((g0 - g2) * (g0 - g2) + (g1 - g3) * (g1 - g3));
    const float gh = sqrtf((g2 - g4) * (g2 - g4) + (g3 - g5) * (g3 - g5));
    const float gax0 = gxc - gw * 0.5f, gay0 = gyc - gh * 0.5f;
    const float gax1 = gxc + gw * 0.5f, gay1 = gyc + gh * 0.5f;
    const float garea = (gax1 - gax0) * (gay1 - gay0);
    const float v1x = g2 - g0, v1y = g3 - g1, v2x = g4 - g0, v2y = g5 - g1;
    const float gt_area = fabsf(v1x * v2y - v1y * v2x) * 0.5f;
    const float mxx = fmaxf(fmaxf(g0, g2), fmaxf(g4, g6));
    const float mnx = fminf(fminf(g0, g2), fminf(g4, g6));
    const float mxy = fmaxf(fmaxf(g1, g3), fmaxf(g5, g7));
    const float mny = fminf(fminf(g1, g3), fminf(g5, g7));
    const float dgx = mxx - mnx, dgy = mxy - mny;
    const float radius = sqrtf(dgx * dgx + dgy * dgy) / 32.0f;
    const float thresh = gt_area / radius;
    const int lab = glabels[b * G_ + g];

    // ---- stage pred boxes (32 q x 8 floats = 64 float4) ----
    if (tid < 64) {
        const float4 v = ((const float4*)(pboxes + ((size_t)b * Q_ + q0) * 8))[tid];
        *(float4*)&pq[tid >> 1][(tid & 1) * 4] = v;
    }
    __syncthreads();
    if (tid < QCHUNK) {
        const float* pr = pq[tid];
        const float p0 = pr[0], p1 = pr[1], p2 = pr[2], p3 = pr[3];
        const float p4 = pr[4], p5v = pr[5], p6 = pr[6], p7 = pr[7];
        const float pxc = (p0 + p2 + p4 + p6) * 0.25f;
        const float pyc = (p1 + p3 + p5v + p7) * 0.25f;
        const float pw = sqrtf((p0 - p2) * (p0 - p2) + (p1 - p3) * (p1 - p3));
        const float ph = sqrtf((p2 - p4) * (p2 - p4) + (p3 - p5v) * (p3 - p5v));
        pq[tid][8]  = pxc;
        pq[tid][9]  = pyc;
        pq[tid][10] = pxc - pw * 0.5f;
        pq[tid][11] = pyc - ph * 0.5f;
        pq[tid][12] = pxc + pw * 0.5f;
        pq[tid][13] = pyc + ph * 0.5f;
        pq[tid][14] = pw * ph;
        fgf[tid] = 0;
    }
    __syncthreads();

    // ---- pass 1: fg mask (any over g) ----
    const int lane0 = ((tid & 63) == 0);
    for (int i = 0; i < QCHUNK / 2; ++i) {
        const int ql = 2 * i + qh;
        const float dx = pq[ql][8] - gxc, dy = pq[ql][9] - gyc;
        const int in = sqrtf(dx * dx + dy * dy) <= thresh;
        const int anyin = __any(in);
        if (anyin && lane0) fgf[ql] = 1;
    }

    // ---- pass 2: full cost + running top-5 iou, per 16-q subchunk ----
    float t0 = -1e38f, t1 = -1e38f, t2 = -1e38f, t3 = -1e38f, t4 = -1e38f;

    for (int sc = 0; sc < QCHUNK / 16; ++sc) {
        __syncthreads();  // protects lbuf/ctile reuse (and fgf on sc==0)
        // focal class-cost table for this subchunk (computed in-kernel)
        for (int j = tid; j < 16 * 80; j += 256)
            lbuf[j] = focal_cost(logits[((size_t)b * Q_ + q0 + sc * 16) * 80 + j]);
        __syncthreads();
        #pragma unroll
        for (int jj = 0; jj < 8; ++jj) {
            const int qls = 2 * jj + qh;       // 0..15 within subchunk
            const int ql  = sc * 16 + qls;
            const int q   = q0 + ql;
            const float4 prA = *(const float4*)&pq[ql][0];
            const float4 prB = *(const float4*)&pq[ql][4];
            const float4 prC = *(const float4*)&pq[ql][8];
            const float4 prD = *(const float4*)&pq[ql][12];
            const float p0 = prA.x, p1 = prA.y, p2 = prA.z, p3 = prA.w;
            const float p4 = prB.x, p5v = prB.y, p6 = prB.z, p7 = prB.w;
            const float pxc = prC.x, pyc = prC.y;
            const float pax0 = prC.z, pay0 = prC.w, pax1 = prD.x, pay1 = prD.y;
            const float parea = prD.z;

            const float l1 = fabsf(p0 - g0) + fabsf(p1 - g1) + fabsf(p2 - g2)
                           + fabsf(p3 - g3) + fabsf(p4 - g4) + fabsf(p5v - g5)
                           + fabsf(p6 - g6) + fabsf(p7 - g7);

            const float ltx = fmaxf(pax0, gax0), lty = fmaxf(pay0, gay0);
            const float rbx = fminf(pax1, gax1), rby = fminf(pay1, gay1);
            const float iw = fmaxf(rbx - ltx, 0.f), ih = fmaxf(rby - lty, 0.f);
            const float inter = iw * ih;
            const float iou = inter / (parea + garea - inter + 1e-8f);

            const float ew = fmaxf(pax1, gax1) - fminf(pax0, gax0);
            const float eh = fmaxf(pay1, gay1) - fminf(pay0, gay0);
            const float cc2 = ew * ew + eh * eh + 1e-8f;
            const float dx = pxc - gxc, dy = pyc - gyc;
            const float diou = iou - (dx * dx + dy * dy) / cc2;

            const float cclass = lbuf[qls * 80 + lab];
            const float cost = 5.f * l1 + 2.f * cclass + 2.f * diou
                             + (fgf[ql] ? 0.f : 10000.f);

            const size_t o = ((size_t)b * Q_ + q) * G_ + g;
            out_cost[o] = cost;
            out_iou[o]  = iou;
            ctile[qls][g] = cost;

            if (iou > t4) {
                if (iou > t0)      { t4 = t3; t3 = t2; t2 = t1; t1 = t0; t0 = iou; }
                else if (iou > t1) { t4 = t3; t3 = t2; t2 = t1; t1 = iou; }
                else if (iou > t2) { t4 = t3; t3 = t2; t2 = iou; }
                else if (iou > t3) { t4 = t3; t3 = iou; }
                else               { t4 = iou; }
            }
        }
        __syncthreads();

        // ---- coalesced costT writeout from LDS tile (16 q x 128 g) ----
        for (int t = tid; t < 16 * G_ / 4; t += 256) {
            const int gg = t >> 2;          // 4 float4 (of q) per g
            const int k  = (t & 3) << 2;
            float4 o;
            o.x = ctile[k + 0][gg]; o.y = ctile[k + 1][gg];
            o.z = ctile[k + 2][gg]; o.w = ctile[k + 3][gg];
            *(float4*)&costT[((size_t)b * G_ + gg) * Q_ + q0 + sc * 16 + k] = o;
        }

        // ---- in-kernel row argmin (first-index tie-break), 16 lanes per q ----
        {
            const int qls  = tid >> 4;      // 0..15
            const int part = tid & 15;
            float v = 1e38f; int mg = 0x7fffffff;
            #pragma unroll
            for (int j = 0; j < 8; ++j) {
                const int gg = part + 16 * j;
                const float c = ctile[qls][gg];
                if (c < v || (c == v && gg < mg)) { v = c; mg = gg; }
            }
            #pragma unroll
            for (int off = 1; off < 16; off <<= 1) {
                const float ov = __shfl_xor(v, off);
                const int   og = __shfl_xor(mg, off);
                if (ov < v || (ov == v && og < mg)) { v = ov; mg = og; }
            }
            if (part == 0) ramin[b * Q_ + q0 + sc * 16 + qls] = mg;
        }
    }

    // ---- merge q-halves of top-5, write single list per (col, chunk) ----
    if (qh == 1) {
        phalf[g][0] = t0; phalf[g][1] = t1; phalf[g][2] = t2;
        phalf[g][3] = t3; phalf[g][4] = t4;
    }
    __syncthreads();
    if (qh == 0) {
        merge5_desc(t0, t1, t2, t3, t4,
                    phalf[g][0], phalf[g][1], phalf[g][2], phalf[g][3], phalf[g][4]);
        const size_t pbase = (((size_t)b * G_ + g) * NCH + ci) * 5;
        piou[pbase + 0] = t0; piou[pbase + 1] = t1; piou[pbase + 2] = t2;
        piou[pbase + 3] = t3; piou[pbase + 4] = t4;
    }
}

// ---------------------------------------------------------------------------
// Kernel B: per-column (block=256): exact bottom-5 of costT column (-> cand),
// top-5 iou from partials -> dyn_k, scatter (cnt, gsel).
// ---------------------------------------------------------------------------
__global__ __launch_bounds__(256) void dynk_scatter_kernel(
    const float* __restrict__ costT,
    const float* __restrict__ piou,
    u64* __restrict__ cand,
    int* __restrict__ cnt,
    int* __restrict__ gsel)
{
    const int col = blockIdx.x;          // b*G + g
    const int b = col >> 7, g = col & 127;
    const int tid = threadIdx.x;
    const int wv = tid >> 6, ln = tid & 63;

    __shared__ u64 wl[4][5];

    // ---- phase 1: per-thread bottom-5 over 16 column elements ----
    const float4* colp = (const float4*)(costT + (size_t)col * Q_);
    u64 k0 = U64MAX, k1 = U64MAX, k2 = U64MAX, k3 = U64MAX, k4 = U64MAX;
    #pragma unroll
    for (int s = 0; s < 4; ++s) {
        const int idx = tid + s * 256;
        const float4 c4 = colp[idx];
        const int qb = idx * 4;
        const float vv[4] = {c4.x, c4.y, c4.z, c4.w};
        #pragma unroll
        for (int j = 0; j < 4; ++j) {
            const u64 kk = packkey(vv[j], qb + j);
            if (kk < k4) {
                if (kk < k0)      { k4 = k3; k3 = k2; k2 = k1; k1 = k0; k0 = kk; }
                else if (kk < k1) { k4 = k3; k3 = k2; k2 = k1; k1 = kk; }
                else if (kk < k2) { k4 = k3; k3 = k2; k2 = kk; }
                else if (kk < k3) { k4 = k3; k3 = kk; }
                else              { k4 = kk; }
            }
        }
    }
    #pragma unroll
    for (int off = 1; off < 64; off <<= 1) {
        merge5_asc(k0, k1, k2, k3, k4,
                   __shfl_xor(k0, off), __shfl_xor(k1, off), __shfl_xor(k2, off),
                   __shfl_xor(k3, off), __shfl_xor(k4, off));
    }
    if (ln == 0) { wl[wv][0] = k0; wl[wv][1] = k1; wl[wv][2] = k2; wl[wv][3] = k3; wl[wv][4] = k4; }
    __syncthreads();

    // ---- phase 2 (wave 0): top-5 iou merge from 128 chunk lists ----
    float t0 = -1e38f, t1 = -1e38f, t2 = -1e38f, t3 = -1e38f, t4 = -1e38f;
    if (tid < 64) {
        const size_t base = (size_t)col * (NCH * 5) + (size_t)tid * 10;
        t0 = piou[base + 0]; t1 = piou[base + 1]; t2 = piou[base + 2];
        t3 = piou[base + 3]; t4 = piou[base + 4];
        merge5_desc(t0, t1, t2, t3, t4,
                    piou[base + 5], piou[base + 6], piou[base + 7],
                    piou[base + 8], piou[base + 9]);
        #pragma unroll
        for (int off = 1; off < 64; off <<= 1) {
            merge5_desc(t0, t1, t2, t3, t4,
                        __shfl_xor(t0, off), __shfl_xor(t1, off), __shfl_xor(t2, off),
                        __shfl_xor(t3, off), __shfl_xor(t4, off));
        }
    }

    if (tid == 0) {
        u64 f0 = wl[0][0], f1 = wl[0][1], f2 = wl[0][2], f3 = wl[0][3], f4 = wl[0][4];
        merge5_asc(f0, f1, f2, f3, f4, wl[1][0], wl[1][1], wl[1][2], wl[1][3], wl[1][4]);
        merge5_asc(f0, f1, f2, f3, f4, wl[2][0], wl[2][1], wl[2][2], wl[2][3], wl[2][4]);
        merge5_asc(f0, f1, f2, f3, f4, wl[3][0], wl[3][1], wl[3][2], wl[3][3], wl[3][4]);
        cand[(size_t)col * 5 + 0] = f0;
        cand[(size_t)col * 5 + 1] = f1;
        cand[(size_t)col * 5 + 2] = f2;
        cand[(size_t)col * 5 + 3] = f3;
        cand[(size_t)col * 5 + 4] = f4;

        const float s = t0 + t1 + t2 + t3 + t4;
        int dynk = (int)s;
        if (dynk < 1) dynk = 1;
        if (dynk > 5) dynk = 5;
        const u64 ks[5] = {f0, f1, f2, f3, f4};
        #pragma unroll
        for (int i = 0; i < 5; ++i) {
            if (i < dynk) {
                const int q = (int)(ks[i] & 0xffffffffu);
                atomicAdd(&cnt[b * Q_ + q], 1);
                gsel[b * Q_ + q] = g;   // only read when cnt==1
            }
        }
    }
}

// ---------------------------------------------------------------------------
// Kernel C: per-batch event-driven refinement loop.
// Hits only land on unmatched rows (matched rows carry >=100000 penalty while
// unmatched row costs < 40000); rows never re-assign; columns never unmatch.
// Wave-parallel fallback refills the column's candidate list with the bottom-5
// currently-unmatched rows (prefix-validity argument).
// ---------------------------------------------------------------------------
__global__ __launch_bounds__(256) void loop_kernel(
    const float* __restrict__ costT,
    const int* __restrict__ cnt,
    const int* __restrict__ gsel,
    const int* __restrict__ ramin,
    const u64* __restrict__ cand,
    int* __restrict__ rmatch_final)
{
    const int b = blockIdx.x, tid = threadIdx.x;
    const int wv = tid >> 6, ln = tid & 63;

    __shared__ short rmatch[Q_];            // 8 KB
    __shared__ unsigned char s_ra[Q_];      // 4 KB
    __shared__ int newh[Q_];                // 16 KB
    __shared__ unsigned char newg[Q_];      // 4 KB
    __shared__ u64 scand[G_][5];            // 5 KB
    __shared__ int ptrs[G_], col_cnt[G_], unm_list[G_], prop[G_], fb_slot[G_], touched[G_];
    __shared__ int n_unm, n_fb, n_touch;

    for (int q = tid; q < Q_; q += 256) {
        const int c  = cnt[b * Q_ + q];
        const int ra = ramin[b * Q_ + q];
        s_ra[q] = (unsigned char)ra;
        newh[q] = 0;
        rmatch[q] = (c == 0) ? (short)-1
                             : (c == 1 ? (short)gsel[b * Q_ + q] : (short)ra);
    }
    if (tid < G_) { col_cnt[tid] = 0; ptrs[tid] = 0; }
    for (int i = tid; i < G_ * 5; i += 256)
        scand[i / 5][i % 5] = cand[(size_t)b * G_ * 5 + i];
    __syncthreads();
    for (int q = tid; q < Q_; q += 256)
        if (rmatch[q] >= 0) atomicAdd(&col_cnt[rmatch[q]], 1);
    __syncthreads();

    for (int it = 0; it < G_; ++it) {
        if (tid == 0) { n_unm = 0; n_fb = 0; n_touch = 0; }
        __syncthreads();
        if (tid < G_ && col_cnt[tid] == 0)
            unm_list[atomicAdd(&n_unm, 1)] = tid;
        __syncthreads();
        const int nu = n_unm;
        if (nu == 0) break;

        // propose: first unmatched candidate, else mark for fallback scan
        if (tid < nu) {
            const int g = unm_list[tid];
            int p = ptrs[g];
            int q = -1;
            while (p < 5) {
                const int cq = (int)(scand[g][p] & 0xffffffffu);
                if (rmatch[cq] < 0) { q = cq; break; }
                ++p;
            }
            ptrs[g] = p;
            prop[tid] = q;
            if (q < 0) fb_slot[atomicAdd(&n_fb, 1)] = tid;
        }
        __syncthreads();

        // wave-parallel fallback: bottom-5 unmatched of the column + refill
        const int nf = n_fb;
        for (int i = wv; i < nf; i += 4) {
            const int slot = fb_slot[i];
            const int g = unm_list[slot];
            const float4* colp = (const float4*)(costT + ((size_t)b * G_ + g) * Q_);
            u64 k0 = U64MAX, k1 = U64MAX, k2 = U64MAX, k3 = U64MAX, k4 = U64MAX;
            #pragma unroll 4
            for (int s = 0; s < Q_ / 256; ++s) {
                const int idx = ln + s * 64;
                const float4 c4 = colp[idx];
                const int qb = idx * 4;
                const float vv[4] = {c4.x, c4.y, c4.z, c4.w};
                #pragma unroll
                for (int j = 0; j < 4; ++j) {
                    if (rmatch[qb + j] < 0) {
                        const u64 kk = packkey(vv[j], qb + j);
                        if (kk < k4) {
                            if (kk < k0)      { k4 = k3; k3 = k2; k2 = k1; k1 = k0; k0 = kk; }
                            else if (kk < k1) { k4 = k3; k3 = k2; k2 = k1; k1 = kk; }
                            else if (kk < k2) { k4 = k3; k3 = k2; k2 = kk; }
                            else if (kk < k3) { k4 = k3; k3 = kk; }
                            else              { k4 = kk; }
                        }
                    }
                }
            }
            #pragma unroll
            for (int off = 1; off < 64; off <<= 1) {
                merge5_asc(k0, k1, k2, k3, k4,
                           __shfl_xor(k0, off), __shfl_xor(k1, off), __shfl_xor(k2, off),
                           __shfl_xor(k3, off), __shfl_xor(k4, off));
            }
            if (ln == 0) {
                scand[g][0] = k0; scand[g][1] = k1; scand[g][2] = k2;
                scand[g][3] = k3; scand[g][4] = k4;
                ptrs[g] = 0;
                prop[slot] = (int)(k0 & 0xffffffffu);
            }
        }
        __syncthreads();

        // hits
        if (tid < nu) {
            const int q = prop[tid];
            newg[q] = (unsigned char)unm_list[tid];  // consumed only when nh==1
            if (atomicAdd(&newh[q], 1) == 0)
                touched[atomicAdd(&n_touch, 1)] = q;
        }
        __syncthreads();

        // resolve (dedup): hits only land on unmatched rows
        const int nt = n_touch;
        if (tid < nt) {
            const int q = touched[tid];
            const int nh = newh[q];
            const int gg = (nh == 1) ? (int)newg[q] : (int)s_ra[q];
            rmatch[q] = (short)gg;
            atomicAdd(&col_cnt[gg], 1);
            newh[q] = 0;
        }
        __syncthreads();
    }

    for (int q = tid; q < Q_; q += 256)
        rmatch_final[b * Q_ + q] = rmatch[q];
}

// ---------------------------------------------------------------------------
// Kernel D: expand rmatch -> full match plane (fully parallel float4 writes).
// ---------------------------------------------------------------------------
__global__ __launch_bounds__(256) void expand_kernel(
    const int* __restrict__ rmatch_final, float* __restrict__ out_match)
{
    const int idx = blockIdx.x * 256 + threadIdx.x;  // float4 index
    const int row = idx >> 5;                        // G/4 = 32 float4 per row
    const int gb  = (idx & 31) << 2;
    const int rm  = rmatch_final[row];
    float4 o;
    o.x = (rm == gb)     ? 1.f : 0.f;
    o.y = (rm == gb + 1) ? 1.f : 0.f;
    o.z = (rm == gb + 2) ? 1.f : 0.f;
    o.w = (rm == gb + 3) ? 1.f : 0.f;
    ((float4*)out_match)[idx] = o;
}

extern "C" void kernel_launch(void* const* d_in, const int* in_sizes, int n_in,
                              void* d_out, int out_size, void* d_ws, size_t ws_size,
                              hipStream_t stream) {
    const float* logits  = (const float*)d_in[0];
    const float* pboxes  = (const float*)d_in[1];
    const float* gboxes  = (const float*)d_in[2];
    const int*   glabels = (const int*)d_in[3];

    float* out = (float*)d_out;
    const size_t BQG = (size_t)B_ * Q_ * G_;
    float* out_match = out;
    float* out_cost  = out + BQG;
    float* out_iou   = out + 2 * BQG;

    // workspace layout (~40 MB)
    char* ws = (char*)d_ws;
    size_t off = 0;
    float* costT  = (float*)(ws + off); off += (size_t)B_ * G_ * Q_ * 4;
    float* piou   = (float*)(ws + off); off += (size_t)B_ * G_ * NCH * 5 * 4;
    u64*   cand   = (u64*)  (ws + off); off += (size_t)B_ * G_ * 5 * 8;
    int*   ramin  = (int*)  (ws + off); off += (size_t)B_ * Q_ * 4;
    int*   cnt    = (int*)  (ws + off); off += (size_t)B_ * Q_ * 4;
    int*   gsel   = (int*)  (ws + off); off += (size_t)B_ * Q_ * 4;
    int*   rmf    = (int*)  (ws + off); off += (size_t)B_ * Q_ * 4;

    hipMemsetAsync(cnt, 0, (size_t)B_ * Q_ * 4, stream);
    fused_cost_kernel<<<dim3(NCH, B_), 256, 0, stream>>>(
        logits, pboxes, gboxes, glabels, out_cost, out_iou, costT, piou, ramin);
    dynk_scatter_kernel<<<B_ * G_, 256, 0, stream>>>(costT, piou, cand, cnt, gsel);
    loop_kernel<<<B_, 256, 0, stream>>>(costT, cnt, gsel, ramin, cand, rmf);
    expand_kernel<<<(int)(BQG / 4 / 256), 256, 0, stream>>>(rmf, out_match);
}

// Round 7
// 201.413 us; speedup vs baseline: 2.9983x; 1.0497x over previous
//
#include <hip/hip_runtime.h>
#include <cstdint>
#include <cstddef>

#define B_ 16
#define Q_ 4096
#define G_ 128
#define C_ 80
#define QCHUNK 16
#define NCH (Q_ / QCHUNK)   // 256 chunks

typedef unsigned long long u64;
#define U64MAX 0xffffffffffffffffull

// pack (cost,q) into a sortable u64 key: asc key order == lex (cost asc, q asc)
__device__ __forceinline__ u64 packkey(float v, int q) {
    unsigned int bts = __float_as_uint(v);
    if (bts == 0x80000000u) bts = 0u;  // -0.0 -> +0.0
    bts = (bts & 0x80000000u) ? ~bts : (bts | 0x80000000u);
    return ((u64)bts << 32) | (unsigned int)q;
}

__device__ __forceinline__ u64 umin64(u64 a, u64 b) { return a < b ? a : b; }
__device__ __forceinline__ u64 umax64(u64 a, u64 b) { return a > b ? a : b; }

// merge two desc-sorted 5-lists -> top-5 desc (branchless network)
__device__ __forceinline__ void merge5_desc(
    float& a0, float& a1, float& a2, float& a3, float& a4,
    float b0, float b1, float b2, float b3, float b4)
{
    const float r0 = fmaxf(a0, b0);
    const float r1 = fmaxf(fmaxf(a1, b1), fminf(a0, b0));
    const float r2 = fmaxf(fmaxf(a2, b2), fmaxf(fminf(a0, b1), fminf(a1, b0)));
    const float r3 = fmaxf(fmaxf(a3, b3),
                     fmaxf(fminf(a0, b2), fmaxf(fminf(a1, b1), fminf(a2, b0))));
    const float r4 = fmaxf(fmaxf(a4, b4),
                     fmaxf(fmaxf(fminf(a0, b3), fminf(a3, b0)),
                           fmaxf(fminf(a1, b2), fminf(a2, b1))));
    a0 = r0; a1 = r1; a2 = r2; a3 = r3; a4 = r4;
}

// merge two asc-sorted 5-lists of u64 keys -> bottom-5 asc
__device__ __forceinline__ void merge5_asc(
    u64& a0, u64& a1, u64& a2, u64& a3, u64& a4,
    u64 b0, u64 b1, u64 b2, u64 b3, u64 b4)
{
    const u64 r0 = umin64(a0, b0);
    const u64 r1 = umin64(umin64(a1, b1), umax64(a0, b0));
    const u64 r2 = umin64(umin64(a2, b2), umin64(umax64(a0, b1), umax64(a1, b0)));
    const u64 r3 = umin64(umin64(a3, b3),
                   umin64(umax64(a0, b2), umin64(umax64(a1, b1), umax64(a2, b0))));
    const u64 r4 = umin64(umin64(a4, b4),
                   umin64(umin64(umax64(a0, b3), umax64(a3, b0)),
                          umin64(umax64(a1, b2), umax64(a2, b1))));
    a0 = r0; a1 = r1; a2 = r2; a3 = r3; a4 = r4;
}

__device__ __forceinline__ float focal_cost(float x) {
    float p;
    if (x >= 0.f) { const float e = expf(-x); p = 1.f / (1.f + e); }
    else          { const float e = expf(x);  p = e / (1.f + e); }
    const float pos = 0.25f * (1.f - p) * (1.f - p) * (-logf(p + 1e-8f));
    const float neg = 0.75f * p * p * (-logf(1.f - p + 1e-8f));
    return pos - neg;
}

// ---------------------------------------------------------------------------
// Kernel A: fused cost/iou + focal (in-LDS) + per-chunk top-5 iou AND
// bottom-5 cost partials + in-kernel row-argmin + coalesced costT via tile.
// Block = (chunk of 16 q's, batch). Thread: g = tid&127, qh = tid>>7.
// LDS ~17 KB -> 8 blocks/CU resident; grid 4096 = 16/CU queued.
// ---------------------------------------------------------------------------
__global__ __launch_bounds__(256) void fused_cost_kernel(
    const float* __restrict__ logits,
    const float* __restrict__ pboxes,
    const float* __restrict__ gboxes,
    const int*   __restrict__ glabels,
    float* __restrict__ out_cost,
    float* __restrict__ out_iou,
    float* __restrict__ costT,
    float* __restrict__ piou,
    u64*   __restrict__ pcost,
    int*   __restrict__ ramin)
{
    const int tid = threadIdx.x;
    const int g   = tid & 127;
    const int qh  = tid >> 7;
    const int ci  = blockIdx.x, b = blockIdx.y;
    const int q0  = ci * QCHUNK;

    __shared__ float pq[QCHUNK][16];
    __shared__ int   fgf[QCHUNK];
    __shared__ __align__(16) char lk_buf[5120];  // lbuf float[1280] -> khalf u64[128][5]
    __shared__ float ctile[QCHUNK][G_ + 1];
    __shared__ float phalf[G_][5];
    float* lbuf = (float*)lk_buf;
    u64 (*khalf)[5] = (u64(*)[5])lk_buf;

    // ---- per-thread gt constants ----
    const float4* gb4 = (const float4*)(gboxes + ((size_t)b * G_ + g) * 8);
    const float4 gA = gb4[0], gB = gb4[1];
    const float g0 = gA.x, g1 = gA.y, g2 = gA.z, g3 = gA.w;
    const float g4 = gB.x, g5 = gB.y, g6 = gB.z, g7 = gB.w;
    const float gxc = (g0 + g2 + g4 + g6) * 0.25f;
    const float gyc = (g1 + g3 + g5 + g7) * 0.25f;
    const float gw = sqrtf((g0 - g2) * (g0 - g2) + (g1 - g3) * (g1 - g3));
    const float gh = sqrtf((g2 - g4) * (g2 - g4) + (g3 - g5) * (g3 - g5));
    const float gax0 = gxc - gw * 0.5f, gay0 = gyc - gh * 0.5f;
    const float gax1 = gxc + gw * 0.5f, gay1 = gyc + gh * 0.5f;
    const float garea = (gax1 - gax0) * (gay1 - gay0);
    const float v1x = g2 - g0, v1y = g3 - g1, v2x = g4 - g0, v2y = g5 - g1;
    const float gt_area = fabsf(v1x * v2y - v1y * v2x) * 0.5f;
    const float mxx = fmaxf(fmaxf(g0, g2), fmaxf(g4, g6));
    const float mnx = fminf(fminf(g0, g2), fminf(g4, g6));
    const float mxy = fmaxf(fmaxf(g1, g3), fmaxf(g5, g7));
    const float mny = fminf(fminf(g1, g3), fminf(g5, g7));
    const float dgx = mxx - mnx, dgy = mxy - mny;
    const float radius = sqrtf(dgx * dgx + dgy * dgy) / 32.0f;
    const float thresh = gt_area / radius;
    const int lab = glabels[b * G_ + g];

    // ---- stage pred boxes (16 q x 8 floats = 32 float4) ----
    if (tid < 32) {
        const float4 v = ((const float4*)(pboxes + ((size_t)b * Q_ + q0) * 8))[tid];
        *(float4*)&pq[tid >> 1][(tid & 1) * 4] = v;
    }
    __syncthreads();
    if (tid < QCHUNK) {
        const float* pr = pq[tid];
        const float p0 = pr[0], p1 = pr[1], p2 = pr[2], p3 = pr[3];
        const float p4 = pr[4], p5v = pr[5], p6 = pr[6], p7 = pr[7];
        const float pxc = (p0 + p2 + p4 + p6) * 0.25f;
        const float pyc = (p1 + p3 + p5v + p7) * 0.25f;
        const float pw = sqrtf((p0 - p2) * (p0 - p2) + (p1 - p3) * (p1 - p3));
        const float ph = sqrtf((p2 - p4) * (p2 - p4) + (p3 - p5v) * (p3 - p5v));
        pq[tid][8]  = pxc;
        pq[tid][9]  = pyc;
        pq[tid][10] = pxc - pw * 0.5f;
        pq[tid][11] = pyc - ph * 0.5f;
        pq[tid][12] = pxc + pw * 0.5f;
        pq[tid][13] = pyc + ph * 0.5f;
        pq[tid][14] = pw * ph;
        fgf[tid] = 0;
    }
    // focal class-cost table for this chunk (16 q x 80 classes)
    __syncthreads();
    for (int j = tid; j < QCHUNK * 80; j += 256)
        lbuf[j] = focal_cost(logits[((size_t)b * Q_ + q0) * 80 + j]);

    // ---- fg mask (any over g); fgf written by lane0 of each wave ----
    const int lane0 = ((tid & 63) == 0);
    for (int i = 0; i < QCHUNK / 2; ++i) {
        const int ql = 2 * i + qh;
        const float dx = pq[ql][8] - gxc, dy = pq[ql][9] - gyc;
        const int in = sqrtf(dx * dx + dy * dy) <= thresh;
        const int anyin = __any(in);
        if (anyin && lane0) fgf[ql] = 1;
    }
    __syncthreads();

    // ---- main loop: full cost + running top-5 iou + bottom-5 cost keys ----
    float t0 = -1e38f, t1 = -1e38f, t2 = -1e38f, t3 = -1e38f, t4 = -1e38f;
    u64 k0 = U64MAX, k1 = U64MAX, k2 = U64MAX, k3 = U64MAX, k4 = U64MAX;

    #pragma unroll
    for (int jj = 0; jj < 8; ++jj) {
        const int qls = 2 * jj + qh;       // 0..15
        const int q   = q0 + qls;
        const float4 prA = *(const float4*)&pq[qls][0];
        const float4 prB = *(const float4*)&pq[qls][4];
        const float4 prC = *(const float4*)&pq[qls][8];
        const float4 prD = *(const float4*)&pq[qls][12];
        const float p0 = prA.x, p1 = prA.y, p2 = prA.z, p3 = prA.w;
        const float p4 = prB.x, p5v = prB.y, p6 = prB.z, p7 = prB.w;
        const float pxc = prC.x, pyc = prC.y;
        const float pax0 = prC.z, pay0 = prC.w, pax1 = prD.x, pay1 = prD.y;
        const float parea = prD.z;

        const float l1 = fabsf(p0 - g0) + fabsf(p1 - g1) + fabsf(p2 - g2)
                       + fabsf(p3 - g3) + fabsf(p4 - g4) + fabsf(p5v - g5)
                       + fabsf(p6 - g6) + fabsf(p7 - g7);

        const float ltx = fmaxf(pax0, gax0), lty = fmaxf(pay0, gay0);
        const float rbx = fminf(pax1, gax1), rby = fminf(pay1, gay1);
        const float iw = fmaxf(rbx - ltx, 0.f), ih = fmaxf(rby - lty, 0.f);
        const float inter = iw * ih;
        const float iou = inter / (parea + garea - inter + 1e-8f);

        const float ew = fmaxf(pax1, gax1) - fminf(pax0, gax0);
        const float eh = fmaxf(pay1, gay1) - fminf(pay0, gay0);
        const float cc2 = ew * ew + eh * eh + 1e-8f;
        const float dx = pxc - gxc, dy = pyc - gyc;
        const float diou = iou - (dx * dx + dy * dy) / cc2;

        const float cclass = lbuf[qls * 80 + lab];
        const float cost = 5.f * l1 + 2.f * cclass + 2.f * diou
                         + (fgf[qls] ? 0.f : 10000.f);

        const size_t o = ((size_t)b * Q_ + q) * G_ + g;
        out_cost[o] = cost;
        out_iou[o]  = iou;
        ctile[qls][g] = cost;

        if (iou > t4) {
            if (iou > t0)      { t4 = t3; t3 = t2; t2 = t1; t1 = t0; t0 = iou; }
            else if (iou > t1) { t4 = t3; t3 = t2; t2 = t1; t1 = iou; }
            else if (iou > t2) { t4 = t3; t3 = t2; t2 = iou; }
            else if (iou > t3) { t4 = t3; t3 = iou; }
            else               { t4 = iou; }
        }
        const u64 kk = packkey(cost, q);
        if (kk < k4) {
            if (kk < k0)      { k4 = k3; k3 = k2; k2 = k1; k1 = k0; k0 = kk; }
            else if (kk < k1) { k4 = k3; k3 = k2; k2 = k1; k1 = kk; }
            else if (kk < k2) { k4 = k3; k3 = k2; k2 = kk; }
            else if (kk < k3) { k4 = k3; k3 = kk; }
            else              { k4 = kk; }
        }
    }
    __syncthreads();   // ctile complete; lbuf reads done (khalf may overlay)

    // ---- coalesced costT writeout from LDS tile (16 q x 128 g) ----
    for (int t = tid; t < QCHUNK * G_ / 4; t += 256) {
        const int gg = t >> 2;          // 4 float4 (of q) per g
        const int k  = (t & 3) << 2;
        float4 o;
        o.x = ctile[k + 0][gg]; o.y = ctile[k + 1][gg];
        o.z = ctile[k + 2][gg]; o.w = ctile[k + 3][gg];
        *(float4*)&costT[((size_t)b * G_ + gg) * Q_ + q0 + k] = o;
    }

    // ---- in-kernel row argmin (first-index tie-break), 16 lanes per q ----
    {
        const int qls  = tid >> 4;      // 0..15
        const int part = tid & 15;
        float v = 1e38f; int mg = 0x7fffffff;
        #pragma unroll
        for (int j = 0; j < 8; ++j) {
            const int gg = part + 16 * j;
            const float c = ctile[qls][gg];
            if (c < v || (c == v && gg < mg)) { v = c; mg = gg; }
        }
        #pragma unroll
        for (int off = 1; off < 16; off <<= 1) {
            const float ov = __shfl_xor(v, off);
            const int   og = __shfl_xor(mg, off);
            if (ov < v || (ov == v && og < mg)) { v = ov; mg = og; }
        }
        if (part == 0) ramin[b * Q_ + q0 + qls] = mg;
    }

    // ---- merge q-halves of both partial lists, write per (col, chunk) ----
    if (qh == 1) {
        phalf[g][0] = t0; phalf[g][1] = t1; phalf[g][2] = t2;
        phalf[g][3] = t3; phalf[g][4] = t4;
        khalf[g][0] = k0; khalf[g][1] = k1; khalf[g][2] = k2;
        khalf[g][3] = k3; khalf[g][4] = k4;
    }
    __syncthreads();
    if (qh == 0) {
        merge5_desc(t0, t1, t2, t3, t4,
                    phalf[g][0], phalf[g][1], phalf[g][2], phalf[g][3], phalf[g][4]);
        merge5_asc(k0, k1, k2, k3, k4,
                   khalf[g][0], khalf[g][1], khalf[g][2], khalf[g][3], khalf[g][4]);
        const size_t pbase = (((size_t)b * G_ + g) * NCH + ci) * 5;
        piou[pbase + 0] = t0; piou[pbase + 1] = t1; piou[pbase + 2] = t2;
        piou[pbase + 3] = t3; piou[pbase + 4] = t4;
        pcost[pbase + 0] = k0; pcost[pbase + 1] = k1; pcost[pbase + 2] = k2;
        pcost[pbase + 3] = k3; pcost[pbase + 4] = k4;
    }
}

// ---------------------------------------------------------------------------
// Kernel B: per-column (block=256 = one thread per chunk-list): merge 256
// sorted 5-lists (cost keys asc, iou desc) -> cand, dyn_k, scatter.
// Reads only partials (~16 MB total) instead of the 134 MB costT.
// ---------------------------------------------------------------------------
__global__ __launch_bounds__(256) void dynk_scatter_kernel(
    const u64*   __restrict__ pcost,
    const float* __restrict__ piou,
    u64* __restrict__ cand,
    int* __restrict__ cnt,
    int* __restrict__ gsel)
{
    const int col = blockIdx.x;          // b*G + g
    const int b = col >> 7, g = col & 127;
    const int tid = threadIdx.x;
    const int wv = tid >> 6, ln = tid & 63;

    __shared__ u64   wl[4][5];
    __shared__ float il[4][5];

    const size_t base = (size_t)col * (NCH * 5) + (size_t)tid * 5;

    u64 k0 = pcost[base + 0], k1 = pcost[base + 1], k2 = pcost[base + 2],
        k3 = pcost[base + 3], k4 = pcost[base + 4];
    float t0 = piou[base + 0], t1 = piou[base + 1], t2 = piou[base + 2],
          t3 = piou[base + 3], t4 = piou[base + 4];

    #pragma unroll
    for (int off = 1; off < 64; off <<= 1) {
        merge5_asc(k0, k1, k2, k3, k4,
                   __shfl_xor(k0, off), __shfl_xor(k1, off), __shfl_xor(k2, off),
                   __shfl_xor(k3, off), __shfl_xor(k4, off));
        merge5_desc(t0, t1, t2, t3, t4,
                    __shfl_xor(t0, off), __shfl_xor(t1, off), __shfl_xor(t2, off),
                    __shfl_xor(t3, off), __shfl_xor(t4, off));
    }
    if (ln == 0) {
        wl[wv][0] = k0; wl[wv][1] = k1; wl[wv][2] = k2; wl[wv][3] = k3; wl[wv][4] = k4;
        il[wv][0] = t0; il[wv][1] = t1; il[wv][2] = t2; il[wv][3] = t3; il[wv][4] = t4;
    }
    __syncthreads();

    if (tid == 0) {
        u64 f0 = wl[0][0], f1 = wl[0][1], f2 = wl[0][2], f3 = wl[0][3], f4 = wl[0][4];
        merge5_asc(f0, f1, f2, f3, f4, wl[1][0], wl[1][1], wl[1][2], wl[1][3], wl[1][4]);
        merge5_asc(f0, f1, f2, f3, f4, wl[2][0], wl[2][1], wl[2][2], wl[2][3], wl[2][4]);
        merge5_asc(f0, f1, f2, f3, f4, wl[3][0], wl[3][1], wl[3][2], wl[3][3], wl[3][4]);
        float s0 = il[0][0], s1 = il[0][1], s2 = il[0][2], s3 = il[0][3], s4 = il[0][4];
        merge5_desc(s0, s1, s2, s3, s4, il[1][0], il[1][1], il[1][2], il[1][3], il[1][4]);
        merge5_desc(s0, s1, s2, s3, s4, il[2][0], il[2][1], il[2][2], il[2][3], il[2][4]);
        merge5_desc(s0, s1, s2, s3, s4, il[3][0], il[3][1], il[3][2], il[3][3], il[3][4]);

        cand[(size_t)col * 5 + 0] = f0;
        cand[(size_t)col * 5 + 1] = f1;
        cand[(size_t)col * 5 + 2] = f2;
        cand[(size_t)col * 5 + 3] = f3;
        cand[(size_t)col * 5 + 4] = f4;

        const float s = s0 + s1 + s2 + s3 + s4;
        int dynk = (int)s;
        if (dynk < 1) dynk = 1;
        if (dynk > 5) dynk = 5;
        const u64 ks[5] = {f0, f1, f2, f3, f4};
        #pragma unroll
        for (int i = 0; i < 5; ++i) {
            if (i < dynk) {
                const int q = (int)(ks[i] & 0xffffffffu);
                atomicAdd(&cnt[b * Q_ + q], 1);
                gsel[b * Q_ + q] = g;   // only read when cnt==1
            }
        }
    }
}

// ---------------------------------------------------------------------------
// Kernel C: per-batch event-driven refinement loop.
// Hits only land on unmatched rows (matched rows carry >=100000 penalty while
// unmatched row costs < 40000); rows never re-assign; columns never unmatch.
// Wave-parallel fallback refills the column's candidate list with the bottom-5
// currently-unmatched rows (prefix-validity argument).
// ---------------------------------------------------------------------------
__global__ __launch_bounds__(256) void loop_kernel(
    const float* __restrict__ costT,
    const int* __restrict__ cnt,
    const int* __restrict__ gsel,
    const int* __restrict__ ramin,
    const u64* __restrict__ cand,
    int* __restrict__ rmatch_final)
{
    const int b = blockIdx.x, tid = threadIdx.x;
    const int wv = tid >> 6, ln = tid & 63;

    __shared__ short rmatch[Q_];            // 8 KB
    __shared__ unsigned char s_ra[Q_];      // 4 KB
    __shared__ int newh[Q_];                // 16 KB
    __shared__ unsigned char newg[Q_];      // 4 KB
    __shared__ u64 scand[G_][5];            // 5 KB
    __shared__ int ptrs[G_], col_cnt[G_], unm_list[G_], prop[G_], fb_slot[G_], touched[G_];
    __shared__ int n_unm, n_fb, n_touch;

    for (int q = tid; q < Q_; q += 256) {
        const int c  = cnt[b * Q_ + q];
        const int ra = ramin[b * Q_ + q];
        s_ra[q] = (unsigned char)ra;
        newh[q] = 0;
        rmatch[q] = (c == 0) ? (short)-1
                             : (c == 1 ? (short)gsel[b * Q_ + q] : (short)ra);
    }
    if (tid < G_) { col_cnt[tid] = 0; ptrs[tid] = 0; }
    for (int i = tid; i < G_ * 5; i += 256)
        scand[i / 5][i % 5] = cand[(size_t)b * G_ * 5 + i];
    __syncthreads();
    for (int q = tid; q < Q_; q += 256)
        if (rmatch[q] >= 0) atomicAdd(&col_cnt[rmatch[q]], 1);
    __syncthreads();

    for (int it = 0; it < G_; ++it) {
        if (tid == 0) { n_unm = 0; n_fb = 0; n_touch = 0; }
        __syncthreads();
        if (tid < G_ && col_cnt[tid] == 0)
            unm_list[atomicAdd(&n_unm, 1)] = tid;
        __syncthreads();
        const int nu = n_unm;
        if (nu == 0) break;

        // propose: first unmatched candidate, else mark for fallback scan
        if (tid < nu) {
            const int g = unm_list[tid];
            int p = ptrs[g];
            int q = -1;
            while (p < 5) {
                const int cq = (int)(scand[g][p] & 0xffffffffu);
                if (rmatch[cq] < 0) { q = cq; break; }
                ++p;
            }
            ptrs[g] = p;
            prop[tid] = q;
            if (q < 0) fb_slot[atomicAdd(&n_fb, 1)] = tid;
        }
        __syncthreads();

        // wave-parallel fallback: bottom-5 unmatched of the column + refill
        const int nf = n_fb;
        for (int i = wv; i < nf; i += 4) {
            const int slot = fb_slot[i];
            const int g = unm_list[slot];
            const float4* colp = (const float4*)(costT + ((size_t)b * G_ + g) * Q_);
            u64 k0 = U64MAX, k1 = U64MAX, k2 = U64MAX, k3 = U64MAX, k4 = U64MAX;
            #pragma unroll 4
            for (int s = 0; s < Q_ / 256; ++s) {
                const int idx = ln + s * 64;
                const float4 c4 = colp[idx];
                const int qb = idx * 4;
                const float vv[4] = {c4.x, c4.y, c4.z, c4.w};
                #pragma unroll
                for (int j = 0; j < 4; ++j) {
                    if (rmatch[qb + j] < 0) {
                        const u64 kk = packkey(vv[j], qb + j);
                        if (kk < k4) {
                            if (kk < k0)      { k4 = k3; k3 = k2; k2 = k1; k1 = k0; k0 = kk; }
                            else if (kk < k1) { k4 = k3; k3 = k2; k2 = k1; k1 = kk; }
                            else if (kk < k2) { k4 = k3; k3 = k2; k2 = kk; }
                            else if (kk < k3) { k4 = k3; k3 = kk; }
                            else              { k4 = kk; }
                        }
                    }
                }
            }
            #pragma unroll
            for (int off = 1; off < 64; off <<= 1) {
                merge5_asc(k0, k1, k2, k3, k4,
                           __shfl_xor(k0, off), __shfl_xor(k1, off), __shfl_xor(k2, off),
                           __shfl_xor(k3, off), __shfl_xor(k4, off));
            }
            if (ln == 0) {
                scand[g][0] = k0; scand[g][1] = k1; scand[g][2] = k2;
                scand[g][3] = k3; scand[g][4] = k4;
                ptrs[g] = 0;
                prop[slot] = (int)(k0 & 0xffffffffu);
            }
        }
        __syncthreads();

        // hits
        if (tid < nu) {
            const int q = prop[tid];
            newg[q] = (unsigned char)unm_list[tid];  // consumed only when nh==1
            if (atomicAdd(&newh[q], 1) == 0)
                touched[atomicAdd(&n_touch, 1)] = q;
        }
        __syncthreads();

        // resolve (dedup): hits only land on unmatched rows
        const int nt = n_touch;
        if (tid < nt) {
            const int q = touched[tid];
            const int nh = newh[q];
            const int gg = (nh == 1) ? (int)newg[q] : (int)s_ra[q];
            rmatch[q] = (short)gg;
            atomicAdd(&col_cnt[gg], 1);
            newh[q] = 0;
        }
        __syncthreads();
    }

    for (int q = tid; q < Q_; q += 256)
        rmatch_final[b * Q_ + q] = rmatch[q];
}

// ---------------------------------------------------------------------------
// Kernel D: expand rmatch -> full match plane (fully parallel float4 writes).
// ---------------------------------------------------------------------------
__global__ __launch_bounds__(256) void expand_kernel(
    const int* __restrict__ rmatch_final, float* __restrict__ out_match)
{
    const int idx = blockIdx.x * 256 + threadIdx.x;  // float4 index
    const int row = idx >> 5;                        // G/4 = 32 float4 per row
    const int gb  = (idx & 31) << 2;
    const int rm  = rmatch_final[row];
    float4 o;
    o.x = (rm == gb)     ? 1.f : 0.f;
    o.y = (rm == gb + 1) ? 1.f : 0.f;
    o.z = (rm == gb + 2) ? 1.f : 0.f;
    o.w = (rm == gb + 3) ? 1.f : 0.f;
    ((float4*)out_match)[idx] = o;
}

extern "C" void kernel_launch(void* const* d_in, const int* in_sizes, int n_in,
                              void* d_out, int out_size, void* d_ws, size_t ws_size,
                              hipStream_t stream) {
    const float* logits  = (const float*)d_in[0];
    const float* pboxes  = (const float*)d_in[1];
    const float* gboxes  = (const float*)d_in[2];
    const int*   glabels = (const int*)d_in[3];

    float* out = (float*)d_out;
    const size_t BQG = (size_t)B_ * Q_ * G_;
    float* out_match = out;
    float* out_cost  = out + BQG;
    float* out_iou   = out + 2 * BQG;

    // workspace layout (~66 MB)
    char* ws = (char*)d_ws;
    size_t off = 0;
    float* costT  = (float*)(ws + off); off += (size_t)B_ * G_ * Q_ * 4;
    u64*   pcost  = (u64*)  (ws + off); off += (size_t)B_ * G_ * NCH * 5 * 8;
    float* piou   = (float*)(ws + off); off += (size_t)B_ * G_ * NCH * 5 * 4;
    u64*   cand   = (u64*)  (ws + off); off += (size_t)B_ * G_ * 5 * 8;
    int*   ramin  = (int*)  (ws + off); off += (size_t)B_ * Q_ * 4;
    int*   cnt    = (int*)  (ws + off); off += (size_t)B_ * Q_ * 4;
    int*   gsel   = (int*)  (ws + off); off += (size_t)B_ * Q_ * 4;
    int*   rmf    = (int*)  (ws + off); off += (size_t)B_ * Q_ * 4;

    hipMemsetAsync(cnt, 0, (size_t)B_ * Q_ * 4, stream);
    fused_cost_kernel<<<dim3(NCH, B_), 256, 0, stream>>>(
        logits, pboxes, gboxes, glabels, out_cost, out_iou, costT, piou, pcost, ramin);
    dynk_scatter_kernel<<<B_ * G_, 256, 0, stream>>>(pcost, piou, cand, cnt, gsel);
    loop_kernel<<<B_, 256, 0, stream>>>(costT, cnt, gsel, ramin, cand, rmf);
    expand_kernel<<<(int)(BQG / 4 / 256), 256, 0, stream>>>(rmf, out_match);
}